// Round 1
// baseline (3478.392 us; speedup 1.0000x reference)
//
#include <hip/hip_runtime.h>
#include <hip/hip_bf16.h>
#include <math.h>

typedef __hip_bfloat16 bf16;

#define D_  1024
#define K_  10
#define B_  16384
#define H_  8
#define HD_ 128

struct alignas(16) BF8 { bf16 v[8]; };
struct alignas(8)  BF4 { bf16 v[4]; };

__device__ __forceinline__ float b2f(bf16 x){ return __bfloat162float(x); }
__device__ __forceinline__ bf16  f2b(float x){ return __float2bfloat16(x); }

// ---------------- row-wise L2 normalize: fn = x / max(||x||,1e-8) ----------
__global__ __launch_bounds__(256) void l2norm_k(const float* __restrict__ x,
                                                float* __restrict__ fn) {
  int b = blockIdx.x, t = threadIdx.x;
  const float4* xr = (const float4*)(x + (size_t)b * D_);
  float4 v = xr[t];
  float p = v.x*v.x + v.y*v.y + v.z*v.z + v.w*v.w;
  #pragma unroll
  for (int o = 32; o > 0; o >>= 1) p += __shfl_down(p, o);
  __shared__ float wsum[4];
  if ((t & 63) == 0) wsum[t >> 6] = p;
  __syncthreads();
  __shared__ float inv_s;
  if (t == 0) inv_s = 1.f / fmaxf(sqrtf(wsum[0]+wsum[1]+wsum[2]+wsum[3]), 1e-8f);
  __syncthreads();
  float iv = inv_s;
  float4 o4 = make_float4(v.x*iv, v.y*iv, v.z*iv, v.w*iv);
  ((float4*)(fn + (size_t)b * D_))[t] = o4;
}

// ---------------- anchor refinement (single block) -------------------------
__global__ __launch_bounds__(256) void anchor_refine_k(
    const float* __restrict__ anchors,
    const float* __restrict__ w1, const float* __restrict__ b1,
    const float* __restrict__ w2, const float* __restrict__ b2,
    float* __restrict__ an, float* __restrict__ na) {
  __shared__ float a_s[K_][D_];      // 40 KB
  __shared__ float h_s[K_][D_/2];    // 20 KB
  __shared__ float red[256];
  __shared__ float nrm[K_];
  int t = threadIdx.x;
  for (int i = t; i < K_*D_; i += 256) a_s[0][i] = anchors[i];
  __syncthreads();
  for (int o = t; o < K_*(D_/2); o += 256) {
    int r = o / (D_/2), j = o % (D_/2);
    float s = b1[j];
    for (int d = 0; d < D_; ++d) s = fmaf(a_s[r][d], w1[(size_t)d*(D_/2)+j], s);
    h_s[r][j] = fmaxf(s, 0.f);
  }
  __syncthreads();
  for (int o = t; o < K_*D_; o += 256) {
    int r = o / D_, j = o % D_;
    float s = b2[j];
    for (int d = 0; d < D_/2; ++d) s = fmaf(h_s[r][d], w2[(size_t)d*D_+j], s);
    // can't update a_s in place while others still read row r? all reads of
    // a_s are done (first matmul consumed it) -> safe after barrier above.
    red[t] = 0.f; // no-op to keep compiler calm
    a_s[r][j] = a_s[r][j] + 0.1f * tanhf(s);
  }
  __syncthreads();
  for (int r = 0; r < K_; ++r) {
    float p = 0.f;
    for (int j = t; j < D_; j += 256) p += a_s[r][j]*a_s[r][j];
    red[t] = p; __syncthreads();
    for (int o = 128; o > 0; o >>= 1) { if (t < o) red[t] += red[t+o]; __syncthreads(); }
    if (t == 0) nrm[r] = red[0];
    __syncthreads();
  }
  for (int o = t; o < K_*D_; o += 256) {
    int r = o / D_;
    float iv = 1.f / fmaxf(sqrtf(nrm[r]), 1e-8f);
    an[o] = a_s[r][o % D_] * iv;
  }
  if (t < K_) {
    float n = nrm[t];
    float iv = 1.f / fmaxf(sqrtf(n), 1e-8f);
    na[t] = n * iv * iv;   // ||an_r||^2
  }
}

// ---------------- K/V projection rows + diversity loss ---------------------
__global__ __launch_bounds__(256) void kv_div_k(
    const float* __restrict__ an,
    const float* __restrict__ k_w, const float* __restrict__ k_b,
    const float* __restrict__ v_w, const float* __restrict__ v_b,
    float* __restrict__ Km, float* __restrict__ Vm, float* __restrict__ divloss) {
  int blk = blockIdx.x, t = threadIdx.x;
  if (blk < 2*K_) {
    int r = blk % K_;
    bool isK = blk < K_;
    const float* w = isK ? k_w : v_w;
    const float* bb = isK ? k_b : v_b;
    float* out = isK ? Km : Vm;
    __shared__ float ar[D_];
    for (int i = t; i < D_; i += 256) ar[i] = an[(size_t)r*D_ + i];
    __syncthreads();
    for (int j = t; j < D_; j += 256) {
      float s = bb[j];
      for (int d = 0; d < D_; ++d) s = fmaf(ar[d], w[(size_t)d*D_ + j], s);
      out[(size_t)r*D_ + j] = s;
    }
  } else {
    __shared__ float dm[45];
    if (t < 45) {
      int i = 0, j = 0, c = t;
      for (i = 0; i < K_; ++i) { int cnt = K_-1-i; if (c < cnt) { j = i+1+c; break; } c -= cnt; }
      float s = 0.f;
      for (int d = 0; d < D_; ++d) { float df = an[(size_t)i*D_+d] - an[(size_t)j*D_+d]; s += df*df; }
      dm[t] = sqrtf(fmaxf(s, 1e-24f));
    }
    __syncthreads();
    if (t == 0) {
      float m = 0.f;
      for (int p = 0; p < 45; ++p) m += dm[p];
      m *= (1.f/45.f);
      *divloss = expf(-fmaxf(m, 1e-6f));
    }
  }
}

// ---------------- generic tiled GEMM with fused epilogue -------------------
// C[M,N] = epi(A[M,Kd] @ Bw[Kd,N] + bias)  row-major everywhere
// EPI 0: bias only; EPI 1: aux + scale*(x); EPI 2: exact GELU
template<int EPI, typename TA, typename TO>
__global__ __launch_bounds__(256) void gemm_k(
    const TA* __restrict__ A, const float* __restrict__ Bw,
    const float* __restrict__ bias, const float* __restrict__ aux,
    TO* __restrict__ out, int M, int N, int Kd, float scale) {
  constexpr int BM = 128, BN = 128, BK = 16;
  __shared__ float As[BK][BM];
  __shared__ float Bs[BK][BN];
  const int tid = threadIdx.x;
  const int tx = tid & 15, ty = tid >> 4;
  const int bm = blockIdx.x * BM, bn = blockIdx.y * BN;
  float acc[8][8] = {};
  const int lrow = tid >> 1, lkh = (tid & 1) * 8;   // A tile: 128 rows x 16 k
  const int bkr  = tid >> 4, bcg = (tid & 15) * 8;  // B tile: 16 k x 128 cols
  for (int k0 = 0; k0 < Kd; k0 += BK) {
    float av[8];
    const TA* ap = A + (size_t)(bm + lrow) * Kd + k0 + lkh;
    if constexpr (sizeof(TA) == 4) {
      float4 a0 = *(const float4*)ap; float4 a1 = *(const float4*)(ap + 4);
      av[0]=a0.x; av[1]=a0.y; av[2]=a0.z; av[3]=a0.w;
      av[4]=a1.x; av[5]=a1.y; av[6]=a1.z; av[7]=a1.w;
    } else {
      BF8 t8 = *(const BF8*)ap;
      #pragma unroll
      for (int j = 0; j < 8; ++j) av[j] = b2f(t8.v[j]);
    }
    const float* bp = Bw + (size_t)(k0 + bkr) * N + bn + bcg;
    float4 b0 = *(const float4*)bp; float4 b1 = *(const float4*)(bp + 4);
    #pragma unroll
    for (int j = 0; j < 8; ++j) As[lkh + j][lrow] = av[j];
    *(float4*)&Bs[bkr][bcg]     = b0;
    *(float4*)&Bs[bkr][bcg + 4] = b1;
    __syncthreads();
    #pragma unroll
    for (int kk = 0; kk < BK; ++kk) {
      float a[8], bb[8];
      *(float4*)&a[0]  = *(const float4*)&As[kk][ty*8];
      *(float4*)&a[4]  = *(const float4*)&As[kk][ty*8+4];
      *(float4*)&bb[0] = *(const float4*)&Bs[kk][tx*8];
      *(float4*)&bb[4] = *(const float4*)&Bs[kk][tx*8+4];
      #pragma unroll
      for (int i = 0; i < 8; ++i)
        #pragma unroll
        for (int j = 0; j < 8; ++j) acc[i][j] = fmaf(a[i], bb[j], acc[i][j]);
    }
    __syncthreads();
  }
  #pragma unroll
  for (int i = 0; i < 8; ++i) {
    const int row = bm + ty*8 + i;
    const int col0 = bn + tx*8;
    float res[8];
    #pragma unroll
    for (int j = 0; j < 8; ++j) {
      float x = acc[i][j] + bias[col0 + j];
      if constexpr (EPI == 1) x = aux[(size_t)row * N + col0 + j] + scale * x;
      if constexpr (EPI == 2) x = 0.5f * x * (1.f + erff(x * 0.70710678118654752f));
      res[j] = x;
    }
    if constexpr (sizeof(TO) == 2) {
      BF8 o;
      #pragma unroll
      for (int j = 0; j < 8; ++j) o.v[j] = f2b(res[j]);
      *(BF8*)&out[(size_t)row * N + col0] = o;
    } else {
      *(float4*)&out[(size_t)row * N + col0]     = *(float4*)&res[0];
      *(float4*)&out[(size_t)row * N + col0 + 4] = *(float4*)&res[4];
    }
  }
}

// ---------------- attention over K=10 anchors + center loss ----------------
__global__ __launch_bounds__(128) void attn_k(
    const bf16* __restrict__ q, const float* __restrict__ fn,
    const float* __restrict__ Km, const float* __restrict__ Vm,
    const float* __restrict__ an, const float* __restrict__ na,
    bf16* __restrict__ att, float* __restrict__ cen_acc) {
  int b = blockIdx.x, t = threadIdx.x;
  __shared__ float qs[D_], fs[D_];
  __shared__ float aw[H_][K_];
  __shared__ float avg[K_];
  __shared__ float red[11][128];
  const bf16* qr = q + (size_t)b * D_;
  const float* fr = fn + (size_t)b * D_;
  {
    BF8 l = ((const BF8*)qr)[t];
    #pragma unroll
    for (int j = 0; j < 8; ++j) qs[t*8 + j] = b2f(l.v[j]);
    float4 f0 = ((const float4*)fr)[2*t], f1 = ((const float4*)fr)[2*t + 1];
    *(float4*)&fs[t*8]     = f0;
    *(float4*)&fs[t*8 + 4] = f1;
  }
  __syncthreads();
  if (t < H_*K_) {
    int h = t / K_, kk = t % K_;
    const float* kr = Km + (size_t)kk*D_ + h*HD_;
    const float* qh = qs + h*HD_;
    float s = 0.f;
    for (int d = 0; d < HD_; ++d) s = fmaf(qh[d], kr[d], s);
    aw[h][kk] = s * 0.08838834764831845f;   // 1/sqrt(128)
  }
  __syncthreads();
  if (t < H_) {
    float m = -1e30f;
    for (int k = 0; k < K_; ++k) m = fmaxf(m, aw[t][k]);
    float e[K_], sum = 0.f;
    for (int k = 0; k < K_; ++k) { e[k] = expf(aw[t][k] - m); sum += e[k]; }
    float inv = 1.f / sum;
    for (int k = 0; k < K_; ++k) aw[t][k] = e[k] * inv;
  }
  __syncthreads();
  if (t < K_) {
    float s = 0.f;
    for (int h = 0; h < H_; ++h) s += aw[h][t];
    avg[t] = s * 0.125f;
  }
  for (int d = t; d < D_; d += 128) {
    int h = d >> 7;
    float s = 0.f;
    for (int k = 0; k < K_; ++k) s = fmaf(aw[h][k], Vm[(size_t)k*D_ + d], s);
    att[(size_t)b*D_ + d] = f2b(s);
  }
  float p[11];
  #pragma unroll
  for (int c = 0; c < 11; ++c) p[c] = 0.f;
  for (int d = t; d < D_; d += 128) {
    float f = fs[d];
    p[10] += f*f;
    #pragma unroll
    for (int k = 0; k < K_; ++k) p[k] = fmaf(f, an[(size_t)k*D_ + d], p[k]);
  }
  #pragma unroll
  for (int c = 0; c < 11; ++c) red[c][t] = p[c];
  __syncthreads();
  if (t < 11) {
    float s = 0.f;
    for (int i = 0; i < 128; ++i) s += red[t][i];
    red[t][0] = s;
  }
  __syncthreads();
  if (t == 0) {
    float ss = red[10][0];
    float c = 0.f;
    for (int k = 0; k < K_; ++k) {
      float d2 = ss + na[k] - 2.f * red[k][0];
      c += avg[k] * sqrtf(fmaxf(d2, 1e-12f));
    }
    atomicAdd(cen_acc, c * (1.f / (float)B_));
  }
}

// ---------------- LayerNorm over rows of bf16 ------------------------------
__global__ __launch_bounds__(256) void ln_k(const bf16* __restrict__ x,
    const float* __restrict__ g, const float* __restrict__ bta,
    bf16* __restrict__ out) {
  int b = blockIdx.x, t = threadIdx.x;
  BF4 ld = ((const BF4*)(x + (size_t)b * D_))[t];
  float v[4];
  #pragma unroll
  for (int j = 0; j < 4; ++j) v[j] = b2f(ld.v[j]);
  float s = v[0]+v[1]+v[2]+v[3];
  #pragma unroll
  for (int o = 32; o > 0; o >>= 1) s += __shfl_down(s, o);
  __shared__ float w1[4], w2[4];
  if ((t & 63) == 0) w1[t >> 6] = s;
  __syncthreads();
  __shared__ float mu_s, rs_s;
  if (t == 0) mu_s = (w1[0]+w1[1]+w1[2]+w1[3]) * (1.f/D_);
  __syncthreads();
  float mu = mu_s;
  float qv = 0.f;
  #pragma unroll
  for (int j = 0; j < 4; ++j) { float d = v[j]-mu; qv += d*d; }
  #pragma unroll
  for (int o = 32; o > 0; o >>= 1) qv += __shfl_down(qv, o);
  if ((t & 63) == 0) w2[t >> 6] = qv;
  __syncthreads();
  if (t == 0) rs_s = rsqrtf((w2[0]+w2[1]+w2[2]+w2[3]) * (1.f/D_) + 1e-5f);
  __syncthreads();
  float rs = rs_s;
  BF4 o;
  #pragma unroll
  for (int j = 0; j < 4; ++j) {
    int col = t*4 + j;
    o.v[j] = f2b((v[j]-mu)*rs*g[col] + bta[col]);
  }
  ((BF4*)(out + (size_t)b * D_))[t] = o;
}

// ---------------- final scalar geo -----------------------------------------
__global__ void geo_k(const float* __restrict__ divl, const float* __restrict__ cen,
                      const float* __restrict__ div_w, const float* __restrict__ cen_w,
                      float* __restrict__ out) {
  float g = fabsf(*div_w) * (*divl) + fabsf(*cen_w) * (*cen);
  out[0] = fminf(fmaxf(g, 0.f), 0.01f);
}

extern "C" void kernel_launch(void* const* d_in, const int* in_sizes, int n_in,
                              void* d_out, int out_size, void* d_ws, size_t ws_size,
                              hipStream_t stream) {
  const float* features = (const float*)d_in[0];
  const float* anchors  = (const float*)d_in[1];
  const float* ar_w1 = (const float*)d_in[2];
  const float* ar_b1 = (const float*)d_in[3];
  const float* ar_w2 = (const float*)d_in[4];
  const float* ar_b2 = (const float*)d_in[5];
  const float* q_w = (const float*)d_in[6];
  const float* q_b = (const float*)d_in[7];
  const float* k_w = (const float*)d_in[8];
  const float* k_b = (const float*)d_in[9];
  const float* v_w = (const float*)d_in[10];
  const float* v_b = (const float*)d_in[11];
  const float* o_w = (const float*)d_in[12];
  const float* o_b = (const float*)d_in[13];
  const float* ln_g = (const float*)d_in[14];
  const float* ln_b = (const float*)d_in[15];
  const float* ff_w1 = (const float*)d_in[16];
  const float* ff_b1 = (const float*)d_in[17];
  const float* ff_w2 = (const float*)d_in[18];
  const float* ff_b2 = (const float*)d_in[19];
  const float* div_w = (const float*)d_in[20];
  const float* cen_w = (const float*)d_in[21];
  float* out = (float*)d_out;

  char* w = (char*)d_ws;
  const size_t sz_fn  = (size_t)B_ * D_ * 4;
  const size_t sz_bf  = (size_t)B_ * D_ * 2;
  const size_t sz_h   = (size_t)B_ * 2048 * 2;
  float* ws_fn  = (float*)w;            w += sz_fn;
  bf16*  ws_q   = (bf16*)w;             w += sz_bf;   // q, later enh
  bf16*  ws_att = (bf16*)w;             w += sz_bf;   // att_pre, later ln out
  bf16*  ws_h   = (bf16*)w;             w += sz_h;
  float* ws_an  = (float*)w;            w += (size_t)K_ * D_ * 4;
  float* ws_k   = (float*)w;            w += (size_t)K_ * D_ * 4;
  float* ws_v   = (float*)w;            w += (size_t)K_ * D_ * 4;
  float* ws_na  = (float*)w;            w += 256;
  float* ws_div = (float*)w;            w += 256;
  float* ws_cen = (float*)w;            w += 256;
  if ((size_t)(w - (char*)d_ws) > ws_size) return;  // insufficient workspace

  hipMemsetAsync(ws_cen, 0, 4, stream);

  l2norm_k<<<B_, 256, 0, stream>>>(features, ws_fn);
  anchor_refine_k<<<1, 256, 0, stream>>>(anchors, ar_w1, ar_b1, ar_w2, ar_b2, ws_an, ws_na);
  kv_div_k<<<2*K_ + 1, 256, 0, stream>>>(ws_an, k_w, k_b, v_w, v_b, ws_k, ws_v, ws_div);

  // q = fn @ q_w + q_b
  gemm_k<0, float, bf16><<<dim3(B_/128, D_/128), 256, 0, stream>>>(
      ws_fn, q_w, q_b, nullptr, ws_q, B_, D_, D_, 0.f);

  attn_k<<<B_, 128, 0, stream>>>(ws_q, ws_fn, ws_k, ws_v, ws_an, ws_na, ws_att, ws_cen);

  // enh = fn + 0.1*(att_pre @ o_w + o_b)   (reuse ws_q)
  gemm_k<1, bf16, bf16><<<dim3(B_/128, D_/128), 256, 0, stream>>>(
      ws_att, o_w, o_b, ws_fn, ws_q, B_, D_, D_, 0.1f);

  // ln = layernorm(enh)  (reuse ws_att)
  ln_k<<<B_, 256, 0, stream>>>(ws_q, ln_g, ln_b, ws_att);

  // h = gelu(ln @ ff_w1 + ff_b1)
  gemm_k<2, bf16, bf16><<<dim3(B_/128, 2048/128), 256, 0, stream>>>(
      ws_att, ff_w1, ff_b1, nullptr, ws_h, B_, 2048, D_, 0.f);

  // final = fn + 0.2*(h @ ff_w2 + ff_b2)  -> d_out (f32)
  gemm_k<1, bf16, float><<<dim3(B_/128, D_/128), 256, 0, stream>>>(
      ws_h, ff_w2, ff_b2, ws_fn, out, B_, D_, 2048, 0.2f);

  geo_k<<<1, 1, 0, stream>>>(ws_div, ws_cen, div_w, cen_w, out + (size_t)B_ * D_);
}

// Round 2
// 1005.352 us; speedup vs baseline: 3.4599x; 3.4599x over previous
//
#include <hip/hip_runtime.h>
#include <hip/hip_bf16.h>
#include <math.h>

typedef __hip_bfloat16 bf16;

#define D_  1024
#define K_  10
#define B_  16384
#define H_  8
#define HD_ 128

struct alignas(16) BF8 { bf16 v[8]; };
struct alignas(8)  BF4 { bf16 v[4]; };

typedef __bf16 bf8v __attribute__((ext_vector_type(8)));
typedef float  f4v  __attribute__((ext_vector_type(4)));

__device__ __forceinline__ float b2f(bf16 x){ return __bfloat162float(x); }
__device__ __forceinline__ bf16  f2b(float x){ return __float2bfloat16(x); }

#define GL2LDS16(g, l) __builtin_amdgcn_global_load_lds( \
    (__attribute__((address_space(1))) void*)(g), \
    (__attribute__((address_space(3))) void*)(l), 16, 0, 0)

// ---------------- row-wise L2 normalize -> bf16 ----------------------------
__global__ __launch_bounds__(256) void l2norm_k(const float* __restrict__ x,
                                                bf16* __restrict__ fnb) {
  int b = blockIdx.x, t = threadIdx.x;
  float4 v = ((const float4*)(x + (size_t)b * D_))[t];
  float p = v.x*v.x + v.y*v.y + v.z*v.z + v.w*v.w;
  #pragma unroll
  for (int o = 32; o > 0; o >>= 1) p += __shfl_down(p, o);
  __shared__ float wsum[4];
  if ((t & 63) == 0) wsum[t >> 6] = p;
  __syncthreads();
  __shared__ float inv_s;
  if (t == 0) inv_s = 1.f / fmaxf(sqrtf(wsum[0]+wsum[1]+wsum[2]+wsum[3]), 1e-8f);
  __syncthreads();
  float iv = inv_s;
  BF4 o;
  o.v[0] = f2b(v.x*iv); o.v[1] = f2b(v.y*iv);
  o.v[2] = f2b(v.z*iv); o.v[3] = f2b(v.w*iv);
  ((BF4*)(fnb + (size_t)b * D_))[t] = o;
}

// ---------------- weight transpose f32[R][C] -> bf16[C][R] -----------------
__global__ __launch_bounds__(256) void wt_k(const float* __restrict__ w,
                                            bf16* __restrict__ wt, int R, int C) {
  __shared__ float tle[32][33];
  int c0 = blockIdx.x * 32, r0 = blockIdx.y * 32;
  int tx = threadIdx.x & 31, ty = threadIdx.x >> 5;
  #pragma unroll
  for (int i = 0; i < 32; i += 8)
    tle[ty + i][tx] = w[(size_t)(r0 + ty + i) * C + c0 + tx];
  __syncthreads();
  #pragma unroll
  for (int i = 0; i < 32; i += 8)
    wt[(size_t)(c0 + ty + i) * R + r0 + tx] = f2b(tle[tx][ty + i]);
}

// ---------------- anchor path ----------------------------------------------
// ar1: h[10][512] = relu(anchors @ w1 + b1)      grid 2 x 256
__global__ __launch_bounds__(256) void ar1_k(const float* __restrict__ anchors,
    const float* __restrict__ w1, const float* __restrict__ b1,
    float* __restrict__ h) {
  __shared__ float a_s[K_][D_];
  int t = threadIdx.x;
  int j = blockIdx.x * 256 + t;
  for (int i = t; i < K_*D_; i += 256) a_s[0][i] = anchors[i];
  __syncthreads();
  float s[K_];
  float bj = b1[j];
  #pragma unroll
  for (int r = 0; r < K_; ++r) s[r] = bj;
  for (int d = 0; d < D_; ++d) {
    float wv = w1[(size_t)d * (D_/2) + j];
    #pragma unroll
    for (int r = 0; r < K_; ++r) s[r] = fmaf(a_s[r][d], wv, s[r]);
  }
  #pragma unroll
  for (int r = 0; r < K_; ++r) h[(size_t)r * (D_/2) + j] = fmaxf(s[r], 0.f);
}

// ar2: an_un[10][1024] = anchors + 0.1*tanh(h @ w2 + b2)   grid 4 x 256
__global__ __launch_bounds__(256) void ar2_k(const float* __restrict__ anchors,
    const float* __restrict__ h, const float* __restrict__ w2,
    const float* __restrict__ b2, float* __restrict__ an_un) {
  __shared__ float h_s[K_][D_/2];
  int t = threadIdx.x;
  int j = blockIdx.x * 256 + t;
  for (int i = t; i < K_*(D_/2); i += 256) h_s[0][i] = h[i];
  __syncthreads();
  float s[K_];
  float bj = b2[j];
  #pragma unroll
  for (int r = 0; r < K_; ++r) s[r] = bj;
  for (int d = 0; d < D_/2; ++d) {
    float wv = w2[(size_t)d * D_ + j];
    #pragma unroll
    for (int r = 0; r < K_; ++r) s[r] = fmaf(h_s[r][d], wv, s[r]);
  }
  #pragma unroll
  for (int r = 0; r < K_; ++r)
    an_un[(size_t)r * D_ + j] = anchors[(size_t)r * D_ + j] + 0.1f * tanhf(s[r]);
}

// ar3: normalize -> an, na; diversity loss     grid 1 x 256
__global__ __launch_bounds__(256) void ar3_k(const float* __restrict__ an_un,
    float* __restrict__ an, float* __restrict__ na, float* __restrict__ divloss) {
  __shared__ float a_s[K_][D_];
  __shared__ float red[256];
  __shared__ float nrm[K_];
  int t = threadIdx.x;
  for (int i = t; i < K_*D_; i += 256) a_s[0][i] = an_un[i];
  __syncthreads();
  for (int r = 0; r < K_; ++r) {
    float p = 0.f;
    for (int j = t; j < D_; j += 256) p += a_s[r][j]*a_s[r][j];
    red[t] = p; __syncthreads();
    for (int o = 128; o > 0; o >>= 1) { if (t < o) red[t] += red[t+o]; __syncthreads(); }
    if (t == 0) nrm[r] = red[0];
    __syncthreads();
  }
  for (int i = t; i < K_*D_; i += 256) {
    int r = i / D_;
    float iv = 1.f / fmaxf(sqrtf(nrm[r]), 1e-8f);
    float v = a_s[0][i] * iv;
    a_s[0][i] = v;
    an[i] = v;
  }
  if (t < K_) {
    float iv = 1.f / fmaxf(sqrtf(nrm[t]), 1e-8f);
    na[t] = nrm[t] * iv * iv;
  }
  __syncthreads();
  __shared__ float dm[45];
  if (t < 45) {
    int i = 0, j = 0, c = t;
    for (i = 0; i < K_; ++i) { int cnt = K_-1-i; if (c < cnt) { j = i+1+c; break; } c -= cnt; }
    float s = 0.f;
    for (int d = 0; d < D_; ++d) { float df = a_s[i][d] - a_s[j][d]; s += df*df; }
    dm[t] = sqrtf(fmaxf(s, 1e-24f));
  }
  __syncthreads();
  if (t == 0) {
    float m = 0.f;
    for (int p = 0; p < 45; ++p) m += dm[p];
    m *= (1.f/45.f);
    *divloss = expf(-fmaxf(m, 1e-6f));
  }
}

// kv: K/V projections of anchors    grid 8 x 256
__global__ __launch_bounds__(256) void kv_k(const float* __restrict__ an,
    const float* __restrict__ k_w, const float* __restrict__ k_b,
    const float* __restrict__ v_w, const float* __restrict__ v_b,
    float* __restrict__ Km, float* __restrict__ Vm) {
  __shared__ float a_s[K_][D_];
  int t = threadIdx.x, blk = blockIdx.x;
  bool isK = blk < 4;
  int j = (blk & 3) * 256 + t;
  const float* w  = isK ? k_w : v_w;
  const float* bb = isK ? k_b : v_b;
  float* outp = isK ? Km : Vm;
  for (int i = t; i < K_*D_; i += 256) a_s[0][i] = an[i];
  __syncthreads();
  float s[K_];
  float bj = bb[j];
  #pragma unroll
  for (int r = 0; r < K_; ++r) s[r] = bj;
  for (int d = 0; d < D_; ++d) {
    float wv = w[(size_t)d * D_ + j];
    #pragma unroll
    for (int r = 0; r < K_; ++r) s[r] = fmaf(a_s[r][d], wv, s[r]);
  }
  #pragma unroll
  for (int r = 0; r < K_; ++r) outp[(size_t)r * D_ + j] = s[r];
}

// ---------------- MFMA GEMM: C[M,N] = epi(A[M,K] @ Bt[N,K]^T + bias) -------
// EPI 0: bias; EPI 1: aux + scale*x (aux bf16); EPI 2: exact GELU
template<int EPI, typename TO>
__global__ __launch_bounds__(256) void mgemm_k(
    const bf16* __restrict__ A, const bf16* __restrict__ Bt,
    const float* __restrict__ bias, const bf16* __restrict__ aux,
    TO* __restrict__ out, int M, int N, int Kd, float scale) {
  constexpr int BM = 128, BN = 128, BK = 32;
  __shared__ bf16 As[BM][BK];   // 8 KB
  __shared__ bf16 Bs[BN][BK];   // 8 KB
  const int tid = threadIdx.x;
  const int nMB = M / BM;
  const int nwg = gridDim.x;
  // XCD-aware bijective swizzle (nwg % 8 == 0 for all our shapes)
  int wg = blockIdx.x;
  wg = (wg & 7) * (nwg >> 3) + (wg >> 3);
  const int mb = wg % nMB, nb = wg / nMB;
  const int bm = mb * BM, bn = nb * BN;

  // staging: thread covers 16B at LDS offset tid*16 (+4096 for second half)
  const int srow = tid >> 2;            // 0..63
  const int sk   = (tid & 3) * 8;
  const bf16* ga = A  + (size_t)(bm + srow) * Kd + sk;
  const bf16* gb = Bt + (size_t)(bn + srow) * Kd + sk;
  const size_t rstep = (size_t)64 * Kd;
  bf16* la = &As[0][0] + tid * 8;
  bf16* lb = &Bs[0][0] + tid * 8;

  const int w    = tid >> 6;
  const int lane = tid & 63;
  const int wr = (w >> 1) * 64, wc = (w & 1) * 64;
  const int fr = lane & 15, fg = lane >> 4;

  f4v acc[4][4];
  const f4v zz = {0.f, 0.f, 0.f, 0.f};
  #pragma unroll
  for (int m = 0; m < 4; ++m)
    #pragma unroll
    for (int n = 0; n < 4; ++n) acc[m][n] = zz;

  for (int k0 = 0; k0 < Kd; k0 += BK) {
    GL2LDS16(ga,         la);
    GL2LDS16(ga + rstep, la + 2048);
    GL2LDS16(gb,         lb);
    GL2LDS16(gb + rstep, lb + 2048);
    __syncthreads();
    bf8v af[4], bf_[4];
    #pragma unroll
    for (int m = 0; m < 4; ++m)
      af[m] = *(const bf8v*)&As[wr + m*16 + fr][fg*8];
    #pragma unroll
    for (int n = 0; n < 4; ++n)
      bf_[n] = *(const bf8v*)&Bs[wc + n*16 + fr][fg*8];
    #pragma unroll
    for (int m = 0; m < 4; ++m)
      #pragma unroll
      for (int n = 0; n < 4; ++n)
        acc[m][n] = __builtin_amdgcn_mfma_f32_16x16x32_bf16(af[m], bf_[n], acc[m][n], 0, 0, 0);
    __syncthreads();
    ga += BK; gb += BK;
  }

  // epilogue: C[row][col], col = fr + n*16, row = fg*4 + r + m*16
  float bv[4];
  #pragma unroll
  for (int n = 0; n < 4; ++n) bv[n] = bias[bn + wc + n*16 + fr];
  #pragma unroll
  for (int m = 0; m < 4; ++m) {
    #pragma unroll
    for (int r = 0; r < 4; ++r) {
      const int row = bm + wr + m*16 + fg*4 + r;
      #pragma unroll
      for (int n = 0; n < 4; ++n) {
        const int col = bn + wc + n*16 + fr;
        float x = acc[m][n][r] + bv[n];
        if constexpr (EPI == 1) x = b2f(aux[(size_t)row * N + col]) + scale * x;
        if constexpr (EPI == 2) x = 0.5f * x * (1.f + erff(x * 0.70710678118654752f));
        if constexpr (sizeof(TO) == 2) out[(size_t)row * N + col] = f2b(x);
        else                           out[(size_t)row * N + col] = x;
      }
    }
  }
}

// ---------------- attention over K=10 anchors + center loss ----------------
__global__ __launch_bounds__(128) void attn_k(
    const bf16* __restrict__ q, const bf16* __restrict__ fn,
    const float* __restrict__ Km, const float* __restrict__ Vm,
    const float* __restrict__ an, const float* __restrict__ na,
    bf16* __restrict__ att, float* __restrict__ cen_acc) {
  int b = blockIdx.x, t = threadIdx.x;
  __shared__ float qs[D_], fs[D_];
  __shared__ float aw[H_][K_];
  __shared__ float avg[K_];
  __shared__ float red[11][128];
  {
    BF8 lq = ((const BF8*)(q  + (size_t)b * D_))[t];
    BF8 lf = ((const BF8*)(fn + (size_t)b * D_))[t];
    #pragma unroll
    for (int j = 0; j < 8; ++j) { qs[t*8 + j] = b2f(lq.v[j]); fs[t*8 + j] = b2f(lf.v[j]); }
  }
  __syncthreads();
  if (t < H_*K_) {
    int h = t / K_, kk = t % K_;
    const float* kr = Km + (size_t)kk*D_ + h*HD_;
    const float* qh = qs + h*HD_;
    float s = 0.f;
    for (int d = 0; d < HD_; ++d) s = fmaf(qh[d], kr[d], s);
    aw[h][kk] = s * 0.08838834764831845f;   // 1/sqrt(128)
  }
  __syncthreads();
  if (t < H_) {
    float m = -1e30f;
    for (int k = 0; k < K_; ++k) m = fmaxf(m, aw[t][k]);
    float e[K_], sum = 0.f;
    for (int k = 0; k < K_; ++k) { e[k] = expf(aw[t][k] - m); sum += e[k]; }
    float inv = 1.f / sum;
    for (int k = 0; k < K_; ++k) aw[t][k] = e[k] * inv;
  }
  __syncthreads();
  if (t < K_) {
    float s = 0.f;
    for (int h = 0; h < H_; ++h) s += aw[h][t];
    avg[t] = s * 0.125f;
  }
  for (int d = t; d < D_; d += 128) {
    int h = d >> 7;
    float s = 0.f;
    for (int k = 0; k < K_; ++k) s = fmaf(aw[h][k], Vm[(size_t)k*D_ + d], s);
    att[(size_t)b*D_ + d] = f2b(s);
  }
  float p[11];
  #pragma unroll
  for (int c = 0; c < 11; ++c) p[c] = 0.f;
  for (int d = t; d < D_; d += 128) {
    float f = fs[d];
    p[10] += f*f;
    #pragma unroll
    for (int k = 0; k < K_; ++k) p[k] = fmaf(f, an[(size_t)k*D_ + d], p[k]);
  }
  #pragma unroll
  for (int c = 0; c < 11; ++c) red[c][t] = p[c];
  __syncthreads();
  if (t < 11) {
    float s = 0.f;
    for (int i = 0; i < 128; ++i) s += red[t][i];
    red[t][0] = s;
  }
  __syncthreads();
  if (t == 0) {
    float ss = red[10][0];
    float c = 0.f;
    for (int k = 0; k < K_; ++k) {
      float d2 = ss + na[k] - 2.f * red[k][0];
      c += avg[k] * sqrtf(fmaxf(d2, 1e-12f));
    }
    atomicAdd(cen_acc, c * (1.f / (float)B_));
  }
}

// ---------------- LayerNorm over rows of bf16 ------------------------------
__global__ __launch_bounds__(256) void ln_k(const bf16* __restrict__ x,
    const float* __restrict__ g, const float* __restrict__ bta,
    bf16* __restrict__ out) {
  int b = blockIdx.x, t = threadIdx.x;
  BF4 ld = ((const BF4*)(x + (size_t)b * D_))[t];
  float v[4];
  #pragma unroll
  for (int j = 0; j < 4; ++j) v[j] = b2f(ld.v[j]);
  float s = v[0]+v[1]+v[2]+v[3];
  #pragma unroll
  for (int o = 32; o > 0; o >>= 1) s += __shfl_down(s, o);
  __shared__ float w1[4], w2[4];
  if ((t & 63) == 0) w1[t >> 6] = s;
  __syncthreads();
  __shared__ float mu_s, rs_s;
  if (t == 0) mu_s = (w1[0]+w1[1]+w1[2]+w1[3]) * (1.f/D_);
  __syncthreads();
  float mu = mu_s;
  float qv = 0.f;
  #pragma unroll
  for (int j = 0; j < 4; ++j) { float d = v[j]-mu; qv += d*d; }
  #pragma unroll
  for (int o = 32; o > 0; o >>= 1) qv += __shfl_down(qv, o);
  if ((t & 63) == 0) w2[t >> 6] = qv;
  __syncthreads();
  if (t == 0) rs_s = rsqrtf((w2[0]+w2[1]+w2[2]+w2[3]) * (1.f/D_) + 1e-5f);
  __syncthreads();
  float rs = rs_s;
  BF4 o;
  #pragma unroll
  for (int j = 0; j < 4; ++j) {
    int col = t*4 + j;
    o.v[j] = f2b((v[j]-mu)*rs*g[col] + bta[col]);
  }
  ((BF4*)(out + (size_t)b * D_))[t] = o;
}

// ---------------- final scalar geo -----------------------------------------
__global__ void geo_k(const float* __restrict__ divl, const float* __restrict__ cen,
                      const float* __restrict__ div_w, const float* __restrict__ cen_w,
                      float* __restrict__ out) {
  float g = fabsf(*div_w) * (*divl) + fabsf(*cen_w) * (*cen);
  out[0] = fminf(fmaxf(g, 0.f), 0.01f);
}

extern "C" void kernel_launch(void* const* d_in, const int* in_sizes, int n_in,
                              void* d_out, int out_size, void* d_ws, size_t ws_size,
                              hipStream_t stream) {
  const float* features = (const float*)d_in[0];
  const float* anchors  = (const float*)d_in[1];
  const float* ar_w1 = (const float*)d_in[2];
  const float* ar_b1 = (const float*)d_in[3];
  const float* ar_w2 = (const float*)d_in[4];
  const float* ar_b2 = (const float*)d_in[5];
  const float* q_w = (const float*)d_in[6];
  const float* q_b = (const float*)d_in[7];
  const float* k_w = (const float*)d_in[8];
  const float* k_b = (const float*)d_in[9];
  const float* v_w = (const float*)d_in[10];
  const float* v_b = (const float*)d_in[11];
  const float* o_w = (const float*)d_in[12];
  const float* o_b = (const float*)d_in[13];
  const float* ln_g = (const float*)d_in[14];
  const float* ln_b = (const float*)d_in[15];
  const float* ff_w1 = (const float*)d_in[16];
  const float* ff_b1 = (const float*)d_in[17];
  const float* ff_w2 = (const float*)d_in[18];
  const float* ff_b2 = (const float*)d_in[19];
  const float* div_w = (const float*)d_in[20];
  const float* cen_w = (const float*)d_in[21];
  float* out = (float*)d_out;

  char* w = (char*)d_ws;
  bf16* ws_fnb = (bf16*)w;  w += (size_t)B_ * D_ * 2;        // 32 MB
  bf16* ws_q   = (bf16*)w;  w += (size_t)B_ * D_ * 2;        // q, later enh
  bf16* ws_att = (bf16*)w;  w += (size_t)B_ * D_ * 2;        // att, later ln
  bf16* ws_h   = (bf16*)w;  w += (size_t)B_ * 2048 * 2;      // 64 MB
  bf16* ws_wq  = (bf16*)w;  w += (size_t)D_ * D_ * 2;
  bf16* ws_wo  = (bf16*)w;  w += (size_t)D_ * D_ * 2;
  bf16* ws_w1t = (bf16*)w;  w += (size_t)D_ * 2048 * 2;
  bf16* ws_w2t = (bf16*)w;  w += (size_t)2048 * D_ * 2;
  float* ws_har = (float*)w;  w += (size_t)K_ * (D_/2) * 4;
  float* ws_anu = (float*)w;  w += (size_t)K_ * D_ * 4;
  float* ws_an  = (float*)w;  w += (size_t)K_ * D_ * 4;
  float* ws_k   = (float*)w;  w += (size_t)K_ * D_ * 4;
  float* ws_v   = (float*)w;  w += (size_t)K_ * D_ * 4;
  float* ws_na  = (float*)w;  w += 256;
  float* ws_div = (float*)w;  w += 256;
  float* ws_cen = (float*)w;  w += 256;
  if ((size_t)(w - (char*)d_ws) > ws_size) return;

  hipMemsetAsync(ws_cen, 0, 4, stream);

  // weight transposes (f32 [K,N] -> bf16 [N,K])
  wt_k<<<dim3(D_/32,   D_/32),   256, 0, stream>>>(q_w,   ws_wq,  D_,   D_);
  wt_k<<<dim3(D_/32,   D_/32),   256, 0, stream>>>(o_w,   ws_wo,  D_,   D_);
  wt_k<<<dim3(2048/32, D_/32),   256, 0, stream>>>(ff_w1, ws_w1t, D_,   2048);
  wt_k<<<dim3(D_/32,   2048/32), 256, 0, stream>>>(ff_w2, ws_w2t, 2048, D_);

  l2norm_k<<<B_, 256, 0, stream>>>(features, ws_fnb);

  // anchor path
  ar1_k<<<2, 256, 0, stream>>>(anchors, ar_w1, ar_b1, ws_har);
  ar2_k<<<4, 256, 0, stream>>>(anchors, ws_har, ar_w2, ar_b2, ws_anu);
  ar3_k<<<1, 256, 0, stream>>>(ws_anu, ws_an, ws_na, ws_div);
  kv_k<<<8, 256, 0, stream>>>(ws_an, k_w, k_b, v_w, v_b, ws_k, ws_v);

  // q = fn @ q_w + q_b
  mgemm_k<0, bf16><<<dim3((B_/128)*(D_/128)), 256, 0, stream>>>(
      ws_fnb, ws_wq, q_b, nullptr, ws_q, B_, D_, D_, 0.f);

  attn_k<<<B_, 128, 0, stream>>>(ws_q, ws_fnb, ws_k, ws_v, ws_an, ws_na, ws_att, ws_cen);

  // enh = fn + 0.1*(att @ o_w + o_b)   (reuse ws_q)
  mgemm_k<1, bf16><<<dim3((B_/128)*(D_/128)), 256, 0, stream>>>(
      ws_att, ws_wo, o_b, ws_fnb, ws_q, B_, D_, D_, 0.1f);

  // ln = layernorm(enh)  (reuse ws_att)
  ln_k<<<B_, 256, 0, stream>>>(ws_q, ln_g, ln_b, ws_att);

  // h = gelu(ln @ ff_w1 + ff_b1)
  mgemm_k<2, bf16><<<dim3((B_/128)*(2048/128)), 256, 0, stream>>>(
      ws_att, ws_w1t, ff_b1, nullptr, ws_h, B_, 2048, D_, 0.f);

  // final = fn + 0.2*(h @ ff_w2 + ff_b2)  -> d_out (f32)
  mgemm_k<1, float><<<dim3((B_/128)*(D_/128)), 256, 0, stream>>>(
      ws_h, ws_w2t, ff_b2, ws_fnb, out, B_, D_, 2048, 0.2f);

  geo_k<<<1, 1, 0, stream>>>(ws_div, ws_cen, div_w, cen_w, out + (size_t)B_ * D_);
}

// Round 3
// 874.205 us; speedup vs baseline: 3.9789x; 1.1500x over previous
//
#include <hip/hip_runtime.h>
#include <hip/hip_bf16.h>
#include <math.h>

typedef __hip_bfloat16 bf16;

#define D_  1024
#define K_  10
#define B_  16384
#define H_  8
#define HD_ 128

struct alignas(16) BF8 { bf16 v[8]; };
struct alignas(8)  BF4 { bf16 v[4]; };

typedef __bf16 bf8v __attribute__((ext_vector_type(8)));
typedef float  f4v  __attribute__((ext_vector_type(4)));

__device__ __forceinline__ float b2f(bf16 x){ return __bfloat162float(x); }
__device__ __forceinline__ bf16  f2b(float x){ return __float2bfloat16(x); }

#define GL2LDS16(g, l) __builtin_amdgcn_global_load_lds( \
    (__attribute__((address_space(1))) void*)(g), \
    (__attribute__((address_space(3))) void*)(l), 16, 0, 0)

// ---------------- row-wise L2 normalize -> bf16 ----------------------------
__global__ __launch_bounds__(256) void l2norm_k(const float* __restrict__ x,
                                                bf16* __restrict__ fnb) {
  int b = blockIdx.x, t = threadIdx.x;
  float4 v = ((const float4*)(x + (size_t)b * D_))[t];
  float p = v.x*v.x + v.y*v.y + v.z*v.z + v.w*v.w;
  #pragma unroll
  for (int o = 32; o > 0; o >>= 1) p += __shfl_down(p, o);
  __shared__ float wsum[4];
  if ((t & 63) == 0) wsum[t >> 6] = p;
  __syncthreads();
  __shared__ float inv_s;
  if (t == 0) inv_s = 1.f / fmaxf(sqrtf(wsum[0]+wsum[1]+wsum[2]+wsum[3]), 1e-8f);
  __syncthreads();
  float iv = inv_s;
  BF4 o;
  o.v[0] = f2b(v.x*iv); o.v[1] = f2b(v.y*iv);
  o.v[2] = f2b(v.z*iv); o.v[3] = f2b(v.w*iv);
  ((BF4*)(fnb + (size_t)b * D_))[t] = o;
}

// ---------------- weight transpose f32[R][C] -> bf16[C][R] -----------------
__global__ __launch_bounds__(256) void wt_k(const float* __restrict__ w,
                                            bf16* __restrict__ wt, int R, int C) {
  __shared__ float tle[32][33];
  int c0 = blockIdx.x * 32, r0 = blockIdx.y * 32;
  int tx = threadIdx.x & 31, ty = threadIdx.x >> 5;
  #pragma unroll
  for (int i = 0; i < 32; i += 8)
    tle[ty + i][tx] = w[(size_t)(r0 + ty + i) * C + c0 + tx];
  __syncthreads();
  #pragma unroll
  for (int i = 0; i < 32; i += 8)
    wt[(size_t)(c0 + ty + i) * R + r0 + tx] = f2b(tle[tx][ty + i]);
}

// ---------------- anchor path ----------------------------------------------
__global__ __launch_bounds__(256) void ar1_k(const float* __restrict__ anchors,
    const float* __restrict__ w1, const float* __restrict__ b1,
    float* __restrict__ h) {
  __shared__ float a_s[K_][D_];
  int t = threadIdx.x;
  int j = blockIdx.x * 256 + t;
  for (int i = t; i < K_*D_; i += 256) a_s[0][i] = anchors[i];
  __syncthreads();
  float s[K_];
  float bj = b1[j];
  #pragma unroll
  for (int r = 0; r < K_; ++r) s[r] = bj;
  for (int d = 0; d < D_; ++d) {
    float wv = w1[(size_t)d * (D_/2) + j];
    #pragma unroll
    for (int r = 0; r < K_; ++r) s[r] = fmaf(a_s[r][d], wv, s[r]);
  }
  #pragma unroll
  for (int r = 0; r < K_; ++r) h[(size_t)r * (D_/2) + j] = fmaxf(s[r], 0.f);
}

__global__ __launch_bounds__(256) void ar2_k(const float* __restrict__ anchors,
    const float* __restrict__ h, const float* __restrict__ w2,
    const float* __restrict__ b2, float* __restrict__ an_un) {
  __shared__ float h_s[K_][D_/2];
  int t = threadIdx.x;
  int j = blockIdx.x * 256 + t;
  for (int i = t; i < K_*(D_/2); i += 256) h_s[0][i] = h[i];
  __syncthreads();
  float s[K_];
  float bj = b2[j];
  #pragma unroll
  for (int r = 0; r < K_; ++r) s[r] = bj;
  for (int d = 0; d < D_/2; ++d) {
    float wv = w2[(size_t)d * D_ + j];
    #pragma unroll
    for (int r = 0; r < K_; ++r) s[r] = fmaf(h_s[r][d], wv, s[r]);
  }
  #pragma unroll
  for (int r = 0; r < K_; ++r)
    an_un[(size_t)r * D_ + j] = anchors[(size_t)r * D_ + j] + 0.1f * tanhf(s[r]);
}

__global__ __launch_bounds__(256) void ar3_k(const float* __restrict__ an_un,
    float* __restrict__ an, float* __restrict__ na, float* __restrict__ divloss) {
  __shared__ float a_s[K_][D_];
  __shared__ float red[256];
  __shared__ float nrm[K_];
  int t = threadIdx.x;
  for (int i = t; i < K_*D_; i += 256) a_s[0][i] = an_un[i];
  __syncthreads();
  for (int r = 0; r < K_; ++r) {
    float p = 0.f;
    for (int j = t; j < D_; j += 256) p += a_s[r][j]*a_s[r][j];
    red[t] = p; __syncthreads();
    for (int o = 128; o > 0; o >>= 1) { if (t < o) red[t] += red[t+o]; __syncthreads(); }
    if (t == 0) nrm[r] = red[0];
    __syncthreads();
  }
  for (int i = t; i < K_*D_; i += 256) {
    int r = i / D_;
    float iv = 1.f / fmaxf(sqrtf(nrm[r]), 1e-8f);
    float v = a_s[0][i] * iv;
    a_s[0][i] = v;
    an[i] = v;
  }
  if (t < K_) {
    float iv = 1.f / fmaxf(sqrtf(nrm[t]), 1e-8f);
    na[t] = nrm[t] * iv * iv;
  }
  __syncthreads();
  __shared__ float dm[45];
  if (t < 45) {
    int i = 0, j = 0, c = t;
    for (i = 0; i < K_; ++i) { int cnt = K_-1-i; if (c < cnt) { j = i+1+c; break; } c -= cnt; }
    float s = 0.f;
    for (int d = 0; d < D_; ++d) { float df = a_s[i][d] - a_s[j][d]; s += df*df; }
    dm[t] = sqrtf(fmaxf(s, 1e-24f));
  }
  __syncthreads();
  if (t == 0) {
    float m = 0.f;
    for (int p = 0; p < 45; ++p) m += dm[p];
    m *= (1.f/45.f);
    *divloss = expf(-fmaxf(m, 1e-6f));
  }
}

__global__ __launch_bounds__(256) void kv_k(const float* __restrict__ an,
    const float* __restrict__ k_w, const float* __restrict__ k_b,
    const float* __restrict__ v_w, const float* __restrict__ v_b,
    float* __restrict__ Km, float* __restrict__ Vm) {
  __shared__ float a_s[K_][D_];
  int t = threadIdx.x, blk = blockIdx.x;
  bool isK = blk < 4;
  int j = (blk & 3) * 256 + t;
  const float* w  = isK ? k_w : v_w;
  const float* bb = isK ? k_b : v_b;
  float* outp = isK ? Km : Vm;
  for (int i = t; i < K_*D_; i += 256) a_s[0][i] = an[i];
  __syncthreads();
  float s[K_];
  float bj = bb[j];
  #pragma unroll
  for (int r = 0; r < K_; ++r) s[r] = bj;
  for (int d = 0; d < D_; ++d) {
    float wv = w[(size_t)d * D_ + j];
    #pragma unroll
    for (int r = 0; r < K_; ++r) s[r] = fmaf(a_s[r][d], wv, s[r]);
  }
  #pragma unroll
  for (int r = 0; r < K_; ++r) outp[(size_t)r * D_ + j] = s[r];
}

// ---------------- MFMA GEMM: C[M,N] = epi(A[M,K] @ Bt[N,K]^T + bias) -------
template<int EPI, typename TO>
__global__ __launch_bounds__(256) void mgemm_k(
    const bf16* __restrict__ A, const bf16* __restrict__ Bt,
    const float* __restrict__ bias, const bf16* __restrict__ aux,
    TO* __restrict__ out, int M, int N, int Kd, float scale) {
  constexpr int BM = 128, BN = 128, BK = 32;
  __shared__ bf16 As[BM][BK];
  __shared__ bf16 Bs[BN][BK];
  const int tid = threadIdx.x;
  const int nMB = M / BM;
  const int nwg = gridDim.x;
  int wg = blockIdx.x;
  wg = (wg & 7) * (nwg >> 3) + (wg >> 3);
  const int mb = wg % nMB, nb = wg / nMB;
  const int bm = mb * BM, bn = nb * BN;

  const int srow = tid >> 2;
  const int sk   = (tid & 3) * 8;
  const bf16* ga = A  + (size_t)(bm + srow) * Kd + sk;
  const bf16* gb = Bt + (size_t)(bn + srow) * Kd + sk;
  const size_t rstep = (size_t)64 * Kd;
  bf16* la = &As[0][0] + tid * 8;
  bf16* lb = &Bs[0][0] + tid * 8;

  const int w    = tid >> 6;
  const int lane = tid & 63;
  const int wr = (w >> 1) * 64, wc = (w & 1) * 64;
  const int fr = lane & 15, fg = lane >> 4;

  f4v acc[4][4];
  const f4v zz = {0.f, 0.f, 0.f, 0.f};
  #pragma unroll
  for (int m = 0; m < 4; ++m)
    #pragma unroll
    for (int n = 0; n < 4; ++n) acc[m][n] = zz;

  for (int k0 = 0; k0 < Kd; k0 += BK) {
    GL2LDS16(ga,         la);
    GL2LDS16(ga + rstep, la + 2048);
    GL2LDS16(gb,         lb);
    GL2LDS16(gb + rstep, lb + 2048);
    __syncthreads();
    bf8v af[4], bf_[4];
    #pragma unroll
    for (int m = 0; m < 4; ++m)
      af[m] = *(const bf8v*)&As[wr + m*16 + fr][fg*8];
    #pragma unroll
    for (int n = 0; n < 4; ++n)
      bf_[n] = *(const bf8v*)&Bs[wc + n*16 + fr][fg*8];
    #pragma unroll
    for (int m = 0; m < 4; ++m)
      #pragma unroll
      for (int n = 0; n < 4; ++n)
        acc[m][n] = __builtin_amdgcn_mfma_f32_16x16x32_bf16(af[m], bf_[n], acc[m][n], 0, 0, 0);
    __syncthreads();
    ga += BK; gb += BK;
  }

  float bv[4];
  #pragma unroll
  for (int n = 0; n < 4; ++n) bv[n] = bias[bn + wc + n*16 + fr];
  #pragma unroll
  for (int m = 0; m < 4; ++m) {
    #pragma unroll
    for (int r = 0; r < 4; ++r) {
      const int row = bm + wr + m*16 + fg*4 + r;
      #pragma unroll
      for (int n = 0; n < 4; ++n) {
        const int col = bn + wc + n*16 + fr;
        float x = acc[m][n][r] + bv[n];
        if constexpr (EPI == 1) x = b2f(aux[(size_t)row * N + col]) + scale * x;
        if constexpr (EPI == 2) x = 0.5f * x * (1.f + erff(x * 0.70710678118654752f));
        if constexpr (sizeof(TO) == 2) out[(size_t)row * N + col] = f2b(x);
        else                           out[(size_t)row * N + col] = x;
      }
    }
  }
}

// ---------------- attention: one WAVE per row ------------------------------
// block = 256 thr (4 waves), handles 32 rows; grid = B/32 = 512
__device__ __forceinline__ BF8 pack8(float4 a, float4 b){
  BF8 o;
  o.v[0]=f2b(a.x); o.v[1]=f2b(a.y); o.v[2]=f2b(a.z); o.v[3]=f2b(a.w);
  o.v[4]=f2b(b.x); o.v[5]=f2b(b.y); o.v[6]=f2b(b.z); o.v[7]=f2b(b.w);
  return o;
}

__global__ __launch_bounds__(256) void attn_k(
    const bf16* __restrict__ q, const bf16* __restrict__ fn,
    const float* __restrict__ Km, const float* __restrict__ Vm,
    const float* __restrict__ an, const float* __restrict__ na,
    bf16* __restrict__ att, float* __restrict__ cen_acc) {
  __shared__ bf16 Kb[K_][D_];   // 20 KB
  __shared__ bf16 Vb[K_][D_];   // 20 KB
  __shared__ bf16 Ab[K_][D_];   // 20 KB
  __shared__ float na_s[K_];
  __shared__ float cred[4];
  const int t = threadIdx.x;

  // stage K/V/an (f32 global -> bf16 LDS), 5 iters of 8 elems per thread
  for (int i = t * 8; i < K_*D_; i += 2048) {
    float4 k0 = *(const float4*)(Km + i), k1 = *(const float4*)(Km + i + 4);
    float4 v0 = *(const float4*)(Vm + i), v1 = *(const float4*)(Vm + i + 4);
    float4 a0 = *(const float4*)(an + i), a1 = *(const float4*)(an + i + 4);
    *(BF8*)(&Kb[0][0] + i) = pack8(k0, k1);
    *(BF8*)(&Vb[0][0] + i) = pack8(v0, v1);
    *(BF8*)(&Ab[0][0] + i) = pack8(a0, a1);
  }
  if (t < K_) na_s[t] = na[t];
  __syncthreads();

  const int wid = t >> 6, lane = t & 63;
  const int d0 = lane * 16;          // this lane's 16 dims; head = lane>>3
  float c_acc = 0.f;
  const int row0 = blockIdx.x * 32 + wid * 8;

  for (int i = 0; i < 8; ++i) {
    const int row = row0 + i;
    const BF8* qr = (const BF8*)(q  + (size_t)row * D_) + lane * 2;
    const BF8* fr = (const BF8*)(fn + (size_t)row * D_) + lane * 2;
    BF8 q0 = qr[0], q1 = qr[1], f0 = fr[0], f1 = fr[1];
    float qv[16], fv[16];
    #pragma unroll
    for (int j = 0; j < 8; ++j) {
      qv[j] = b2f(q0.v[j]); qv[8+j] = b2f(q1.v[j]);
      fv[j] = b2f(f0.v[j]); fv[8+j] = b2f(f1.v[j]);
    }
    // QK^T: per-anchor 16-FMA + 3-step 8-lane (head-group) reduce
    float p[K_];
    #pragma unroll
    for (int k = 0; k < K_; ++k) {
      BF8 ka = *(const BF8*)&Kb[k][d0];
      BF8 kb = *(const BF8*)&Kb[k][d0 + 8];
      float s = 0.f;
      #pragma unroll
      for (int j = 0; j < 8; ++j) {
        s = fmaf(qv[j],   b2f(ka.v[j]), s);
        s = fmaf(qv[8+j], b2f(kb.v[j]), s);
      }
      s += __shfl_xor(s, 1); s += __shfl_xor(s, 2); s += __shfl_xor(s, 4);
      p[k] = s * 0.08838834764831845f;
    }
    // softmax over 10 (redundant across the 8 lanes of the head, all same)
    float m = p[0];
    #pragma unroll
    for (int k = 1; k < K_; ++k) m = fmaxf(m, p[k]);
    float sum = 0.f;
    #pragma unroll
    for (int k = 0; k < K_; ++k) { p[k] = __expf(p[k] - m); sum += p[k]; }
    float inv = 1.f / sum;
    #pragma unroll
    for (int k = 0; k < K_; ++k) p[k] *= inv;   // p[k] = aw[head(lane)][k]
    // PV: this lane's 16 output dims
    float ov[16];
    #pragma unroll
    for (int j = 0; j < 16; ++j) ov[j] = 0.f;
    #pragma unroll
    for (int k = 0; k < K_; ++k) {
      BF8 va = *(const BF8*)&Vb[k][d0];
      BF8 vb = *(const BF8*)&Vb[k][d0 + 8];
      #pragma unroll
      for (int j = 0; j < 8; ++j) {
        ov[j]   = fmaf(p[k], b2f(va.v[j]), ov[j]);
        ov[8+j] = fmaf(p[k], b2f(vb.v[j]), ov[8+j]);
      }
    }
    BF8 o0, o1;
    #pragma unroll
    for (int j = 0; j < 8; ++j) { o0.v[j] = f2b(ov[j]); o1.v[j] = f2b(ov[8+j]); }
    BF8* ow = (BF8*)(att + (size_t)row * D_) + lane * 2;
    ow[0] = o0; ow[1] = o1;
    // center loss: dist[k] = sqrt(1 + ||an_k||^2 - 2 fn.an_k)  (||fn||=1)
    #pragma unroll
    for (int k = 0; k < K_; ++k) {
      BF8 aa = *(const BF8*)&Ab[k][d0];
      BF8 ab = *(const BF8*)&Ab[k][d0 + 8];
      float s = 0.f;
      #pragma unroll
      for (int j = 0; j < 8; ++j) {
        s = fmaf(fv[j],   b2f(aa.v[j]), s);
        s = fmaf(fv[8+j], b2f(ab.v[j]), s);
      }
      #pragma unroll
      for (int o = 1; o < 64; o <<= 1) s += __shfl_xor(s, o);
      float dist = sqrtf(fmaxf(1.f + na_s[k] - 2.f * s, 1e-12f));
      c_acc = fmaf(p[k], dist, c_acc);   // wave-sum = 64 * avg-weighted dist
    }
  }
  // reduce c_acc: wave -> block -> global
  #pragma unroll
  for (int o = 1; o < 64; o <<= 1) c_acc += __shfl_xor(c_acc, o);
  if (lane == 0) cred[wid] = c_acc;
  __syncthreads();
  if (t == 0) {
    float s = (cred[0] + cred[1] + cred[2] + cred[3]) * (1.f / 64.f / (float)B_);
    atomicAdd(cen_acc, s);
  }
}

// ---------------- LayerNorm over rows of bf16 ------------------------------
__global__ __launch_bounds__(256) void ln_k(const bf16* __restrict__ x,
    const float* __restrict__ g, const float* __restrict__ bta,
    bf16* __restrict__ out) {
  int b = blockIdx.x, t = threadIdx.x;
  BF4 ld = ((const BF4*)(x + (size_t)b * D_))[t];
  float v[4];
  #pragma unroll
  for (int j = 0; j < 4; ++j) v[j] = b2f(ld.v[j]);
  float s = v[0]+v[1]+v[2]+v[3];
  #pragma unroll
  for (int o = 32; o > 0; o >>= 1) s += __shfl_down(s, o);
  __shared__ float w1[4], w2[4];
  if ((t & 63) == 0) w1[t >> 6] = s;
  __syncthreads();
  __shared__ float mu_s, rs_s;
  if (t == 0) mu_s = (w1[0]+w1[1]+w1[2]+w1[3]) * (1.f/D_);
  __syncthreads();
  float mu = mu_s;
  float qv = 0.f;
  #pragma unroll
  for (int j = 0; j < 4; ++j) { float d = v[j]-mu; qv += d*d; }
  #pragma unroll
  for (int o = 32; o > 0; o >>= 1) qv += __shfl_down(qv, o);
  if ((t & 63) == 0) w2[t >> 6] = qv;
  __syncthreads();
  if (t == 0) rs_s = rsqrtf((w2[0]+w2[1]+w2[2]+w2[3]) * (1.f/D_) + 1e-5f);
  __syncthreads();
  float rs = rs_s;
  BF4 o;
  #pragma unroll
  for (int j = 0; j < 4; ++j) {
    int col = t*4 + j;
    o.v[j] = f2b((v[j]-mu)*rs*g[col] + bta[col]);
  }
  ((BF4*)(out + (size_t)b * D_))[t] = o;
}

// ---------------- final scalar geo -----------------------------------------
__global__ void geo_k(const float* __restrict__ divl, const float* __restrict__ cen,
                      const float* __restrict__ div_w, const float* __restrict__ cen_w,
                      float* __restrict__ out) {
  float g = fabsf(*div_w) * (*divl) + fabsf(*cen_w) * (*cen);
  out[0] = fminf(fmaxf(g, 0.f), 0.01f);
}

extern "C" void kernel_launch(void* const* d_in, const int* in_sizes, int n_in,
                              void* d_out, int out_size, void* d_ws, size_t ws_size,
                              hipStream_t stream) {
  const float* features = (const float*)d_in[0];
  const float* anchors  = (const float*)d_in[1];
  const float* ar_w1 = (const float*)d_in[2];
  const float* ar_b1 = (const float*)d_in[3];
  const float* ar_w2 = (const float*)d_in[4];
  const float* ar_b2 = (const float*)d_in[5];
  const float* q_w = (const float*)d_in[6];
  const float* q_b = (const float*)d_in[7];
  const float* k_w = (const float*)d_in[8];
  const float* k_b = (const float*)d_in[9];
  const float* v_w = (const float*)d_in[10];
  const float* v_b = (const float*)d_in[11];
  const float* o_w = (const float*)d_in[12];
  const float* o_b = (const float*)d_in[13];
  const float* ln_g = (const float*)d_in[14];
  const float* ln_b = (const float*)d_in[15];
  const float* ff_w1 = (const float*)d_in[16];
  const float* ff_b1 = (const float*)d_in[17];
  const float* ff_w2 = (const float*)d_in[18];
  const float* ff_b2 = (const float*)d_in[19];
  const float* div_w = (const float*)d_in[20];
  const float* cen_w = (const float*)d_in[21];
  float* out = (float*)d_out;

  char* w = (char*)d_ws;
  bf16* ws_fnb = (bf16*)w;  w += (size_t)B_ * D_ * 2;
  bf16* ws_q   = (bf16*)w;  w += (size_t)B_ * D_ * 2;
  bf16* ws_att = (bf16*)w;  w += (size_t)B_ * D_ * 2;
  bf16* ws_h   = (bf16*)w;  w += (size_t)B_ * 2048 * 2;
  bf16* ws_wq  = (bf16*)w;  w += (size_t)D_ * D_ * 2;
  bf16* ws_wo  = (bf16*)w;  w += (size_t)D_ * D_ * 2;
  bf16* ws_w1t = (bf16*)w;  w += (size_t)D_ * 2048 * 2;
  bf16* ws_w2t = (bf16*)w;  w += (size_t)2048 * D_ * 2;
  float* ws_har = (float*)w;  w += (size_t)K_ * (D_/2) * 4;
  float* ws_anu = (float*)w;  w += (size_t)K_ * D_ * 4;
  float* ws_an  = (float*)w;  w += (size_t)K_ * D_ * 4;
  float* ws_k   = (float*)w;  w += (size_t)K_ * D_ * 4;
  float* ws_v   = (float*)w;  w += (size_t)K_ * D_ * 4;
  float* ws_na  = (float*)w;  w += 256;
  float* ws_div = (float*)w;  w += 256;
  float* ws_cen = (float*)w;  w += 256;
  if ((size_t)(w - (char*)d_ws) > ws_size) return;

  hipMemsetAsync(ws_cen, 0, 4, stream);

  wt_k<<<dim3(D_/32,   D_/32),   256, 0, stream>>>(q_w,   ws_wq,  D_,   D_);
  wt_k<<<dim3(D_/32,   D_/32),   256, 0, stream>>>(o_w,   ws_wo,  D_,   D_);
  wt_k<<<dim3(2048/32, D_/32),   256, 0, stream>>>(ff_w1, ws_w1t, D_,   2048);
  wt_k<<<dim3(D_/32,   2048/32), 256, 0, stream>>>(ff_w2, ws_w2t, 2048, D_);

  l2norm_k<<<B_, 256, 0, stream>>>(features, ws_fnb);

  ar1_k<<<2, 256, 0, stream>>>(anchors, ar_w1, ar_b1, ws_har);
  ar2_k<<<4, 256, 0, stream>>>(anchors, ws_har, ar_w2, ar_b2, ws_anu);
  ar3_k<<<1, 256, 0, stream>>>(ws_anu, ws_an, ws_na, ws_div);
  kv_k<<<8, 256, 0, stream>>>(ws_an, k_w, k_b, v_w, v_b, ws_k, ws_v);

  mgemm_k<0, bf16><<<dim3((B_/128)*(D_/128)), 256, 0, stream>>>(
      ws_fnb, ws_wq, q_b, nullptr, ws_q, B_, D_, D_, 0.f);

  attn_k<<<B_/32, 256, 0, stream>>>(ws_q, ws_fnb, ws_k, ws_v, ws_an, ws_na, ws_att, ws_cen);

  mgemm_k<1, bf16><<<dim3((B_/128)*(D_/128)), 256, 0, stream>>>(
      ws_att, ws_wo, o_b, ws_fnb, ws_q, B_, D_, D_, 0.1f);

  ln_k<<<B_, 256, 0, stream>>>(ws_q, ln_g, ln_b, ws_att);

  mgemm_k<2, bf16><<<dim3((B_/128)*(2048/128)), 256, 0, stream>>>(
      ws_att, ws_w1t, ff_b1, nullptr, ws_h, B_, 2048, D_, 0.f);

  mgemm_k<1, float><<<dim3((B_/128)*(D_/128)), 256, 0, stream>>>(
      ws_h, ws_w2t, ff_b2, ws_fnb, out, B_, D_, 2048, 0.2f);

  geo_k<<<1, 1, 0, stream>>>(ws_div, ws_cen, div_w, cen_w, out + (size_t)B_ * D_);
}

// Round 4
// 613.183 us; speedup vs baseline: 5.6727x; 1.4257x over previous
//
#include <hip/hip_runtime.h>
#include <hip/hip_bf16.h>
#include <math.h>

typedef __hip_bfloat16 bf16;

#define D_  1024
#define K_  10
#define B_  16384
#define H_  8
#define HD_ 128

struct alignas(16) BF8 { bf16 v[8]; };
struct alignas(8)  BF4 { bf16 v[4]; };

typedef __bf16 bf8v __attribute__((ext_vector_type(8)));
typedef float  f4v  __attribute__((ext_vector_type(4)));

__device__ __forceinline__ float b2f(bf16 x){ return __bfloat162float(x); }
__device__ __forceinline__ bf16  f2b(float x){ return __float2bfloat16(x); }

#define GL2LDS16(g, l) __builtin_amdgcn_global_load_lds( \
    (__attribute__((address_space(1))) void*)(g), \
    (__attribute__((address_space(3))) void*)(l), 16, 0, 0)

// ---------------- row-wise L2 normalize -> bf16 ----------------------------
__global__ __launch_bounds__(256) void l2norm_k(const float* __restrict__ x,
                                                bf16* __restrict__ fnb) {
  int b = blockIdx.x, t = threadIdx.x;
  float4 v = ((const float4*)(x + (size_t)b * D_))[t];
  float p = v.x*v.x + v.y*v.y + v.z*v.z + v.w*v.w;
  #pragma unroll
  for (int o = 32; o > 0; o >>= 1) p += __shfl_down(p, o);
  __shared__ float wsum[4];
  if ((t & 63) == 0) wsum[t >> 6] = p;
  __syncthreads();
  __shared__ float inv_s;
  if (t == 0) inv_s = 1.f / fmaxf(sqrtf(wsum[0]+wsum[1]+wsum[2]+wsum[3]), 1e-8f);
  __syncthreads();
  float iv = inv_s;
  BF4 o;
  o.v[0] = f2b(v.x*iv); o.v[1] = f2b(v.y*iv);
  o.v[2] = f2b(v.z*iv); o.v[3] = f2b(v.w*iv);
  ((BF4*)(fnb + (size_t)b * D_))[t] = o;
}

// ---------------- weight transpose f32[R][C] -> bf16[C][R] -----------------
__global__ __launch_bounds__(256) void wt_k(const float* __restrict__ w,
                                            bf16* __restrict__ wt, int R, int C) {
  __shared__ float tle[32][33];
  int c0 = blockIdx.x * 32, r0 = blockIdx.y * 32;
  int tx = threadIdx.x & 31, ty = threadIdx.x >> 5;
  #pragma unroll
  for (int i = 0; i < 32; i += 8)
    tle[ty + i][tx] = w[(size_t)(r0 + ty + i) * C + c0 + tx];
  __syncthreads();
  #pragma unroll
  for (int i = 0; i < 32; i += 8)
    wt[(size_t)(c0 + ty + i) * R + r0 + tx] = f2b(tle[tx][ty + i]);
}

// ---------------- small panel GEMM: out[10][N] = act(A[10][KD] @ W + b) ----
// block covers COLS output columns; 256/COLS thread-groups split KD.
// ACT 0: none; 1: relu; 2: aux + 0.1*tanh(x)
// Second matrix (W2/bias2/out2) handled by blocks [npanel, 2*npanel).
template<int COLS, int KD, int ACT>
__global__ __launch_bounds__(256) void panelmm_k(
    const float* __restrict__ A, const float* __restrict__ W,
    const float* __restrict__ bias, const float* __restrict__ aux,
    float* __restrict__ out,
    const float* __restrict__ W2, const float* __restrict__ bias2,
    float* __restrict__ out2, int N, int npanel) {
  constexpr int GROUPS = 256 / COLS;
  constexpr int DCH = KD / GROUPS;
  __shared__ float A_s[K_][KD];
  __shared__ float part[K_][COLS][GROUPS];
  const int t = threadIdx.x;
  int blk = blockIdx.x;
  const float* Wm = W; const float* bm = bias; float* om = out;
  if (blk >= npanel) { blk -= npanel; Wm = W2; bm = bias2; om = out2; }
  const int panel = blk;
  for (int i = t; i < K_*KD; i += 256) A_s[0][i] = A[i];
  __syncthreads();
  const int cg = t % COLS, g = t / COLS;
  const int col = panel*COLS + cg;
  float s[K_];
  #pragma unroll
  for (int r = 0; r < K_; ++r) s[r] = 0.f;
  const float* wp = Wm + (size_t)(g*DCH)*N + col;
  for (int d = g*DCH; d < (g+1)*DCH; ++d) {
    float wv = *wp; wp += N;
    #pragma unroll
    for (int r = 0; r < K_; ++r) s[r] = fmaf(A_s[r][d], wv, s[r]);
  }
  #pragma unroll
  for (int r = 0; r < K_; ++r) part[r][cg][g] = s[r];
  __syncthreads();
  for (int o = t; o < K_*COLS; o += 256) {
    int r = o / COLS, c = o % COLS;
    float v = 0.f;
    #pragma unroll
    for (int gg = 0; gg < GROUPS; ++gg) v += part[r][c][gg];
    v += bm[panel*COLS + c];
    if constexpr (ACT == 1) v = fmaxf(v, 0.f);
    if constexpr (ACT == 2) v = aux[(size_t)r*N + panel*COLS + c] + 0.1f*tanhf(v);
    om[(size_t)r*N + panel*COLS + c] = v;
  }
}

// ---------------- ar3: normalize anchors + diversity loss ------------------
__global__ __launch_bounds__(256) void ar3_k(const float* __restrict__ an_un,
    float* __restrict__ an, float* __restrict__ na, float* __restrict__ divloss) {
  __shared__ float a_s[K_][D_];
  __shared__ float nrm[K_];
  __shared__ float dm[45];
  const int t = threadIdx.x;
  for (int i = t; i < K_*D_; i += 256) a_s[0][i] = an_un[i];
  __syncthreads();
  const int wid = t >> 6, lane = t & 63;
  for (int r = wid; r < K_; r += 4) {
    float p = 0.f;
    for (int j = lane; j < D_; j += 64) p += a_s[r][j]*a_s[r][j];
    #pragma unroll
    for (int o = 1; o < 64; o <<= 1) p += __shfl_xor(p, o);
    if (lane == 0) nrm[r] = p;
  }
  __syncthreads();
  for (int i = t; i < K_*D_; i += 256) {
    int r = i >> 10;
    float iv = 1.f / fmaxf(sqrtf(nrm[r]), 1e-8f);
    float v = a_s[0][i] * iv;
    a_s[0][i] = v;
    an[i] = v;
  }
  if (t < K_) {
    float iv = 1.f / fmaxf(sqrtf(nrm[t]), 1e-8f);
    na[t] = nrm[t] * iv * iv;
  }
  __syncthreads();
  const int pr = t >> 2, sub = t & 3;
  if (pr < 45) {
    int i = 0, j = 0, c = pr;
    for (i = 0; i < K_; ++i) { int cnt = K_-1-i; if (c < cnt) { j = i+1+c; break; } c -= cnt; }
    float s = 0.f;
    for (int d = sub*256; d < sub*256 + 256; ++d) {
      float df = a_s[i][d] - a_s[j][d]; s += df*df;
    }
    s += __shfl_xor(s, 1); s += __shfl_xor(s, 2);
    if (sub == 0) dm[pr] = sqrtf(fmaxf(s, 1e-24f));
  }
  __syncthreads();
  if (t == 0) {
    float m = 0.f;
    for (int p = 0; p < 45; ++p) m += dm[p];
    m *= (1.f/45.f);
    *divloss = expf(-fmaxf(m, 1e-6f));
  }
}

// ---------------- MFMA GEMM: C[M,N] = epi(A[M,K] @ Bt[N,K]^T + bias) -------
template<int EPI, typename TO>
__global__ __launch_bounds__(256) void mgemm_k(
    const bf16* __restrict__ A, const bf16* __restrict__ Bt,
    const float* __restrict__ bias, const bf16* __restrict__ aux,
    TO* __restrict__ out, int M, int N, int Kd, float scale) {
  constexpr int BM = 128, BN = 128, BK = 32;
  __shared__ bf16 As[BM][BK];
  __shared__ bf16 Bs[BN][BK];
  const int tid = threadIdx.x;
  const int nMB = M / BM;
  const int nwg = gridDim.x;
  int wg = blockIdx.x;
  wg = (wg & 7) * (nwg >> 3) + (wg >> 3);
  const int mb = wg % nMB, nb = wg / nMB;
  const int bm = mb * BM, bn = nb * BN;

  const int srow = tid >> 2;
  const int sk   = (tid & 3) * 8;
  const bf16* ga = A  + (size_t)(bm + srow) * Kd + sk;
  const bf16* gb = Bt + (size_t)(bn + srow) * Kd + sk;
  const size_t rstep = (size_t)64 * Kd;
  bf16* la = &As[0][0] + tid * 8;
  bf16* lb = &Bs[0][0] + tid * 8;

  const int w    = tid >> 6;
  const int lane = tid & 63;
  const int wr = (w >> 1) * 64, wc = (w & 1) * 64;
  const int fr = lane & 15, fg = lane >> 4;

  f4v acc[4][4];
  const f4v zz = {0.f, 0.f, 0.f, 0.f};
  #pragma unroll
  for (int m = 0; m < 4; ++m)
    #pragma unroll
    for (int n = 0; n < 4; ++n) acc[m][n] = zz;

  for (int k0 = 0; k0 < Kd; k0 += BK) {
    GL2LDS16(ga,         la);
    GL2LDS16(ga + rstep, la + 2048);
    GL2LDS16(gb,         lb);
    GL2LDS16(gb + rstep, lb + 2048);
    __syncthreads();
    bf8v af[4], bf_[4];
    #pragma unroll
    for (int m = 0; m < 4; ++m)
      af[m] = *(const bf8v*)&As[wr + m*16 + fr][fg*8];
    #pragma unroll
    for (int n = 0; n < 4; ++n)
      bf_[n] = *(const bf8v*)&Bs[wc + n*16 + fr][fg*8];
    #pragma unroll
    for (int m = 0; m < 4; ++m)
      #pragma unroll
      for (int n = 0; n < 4; ++n)
        acc[m][n] = __builtin_amdgcn_mfma_f32_16x16x32_bf16(af[m], bf_[n], acc[m][n], 0, 0, 0);
    __syncthreads();
    ga += BK; gb += BK;
  }

  float bv[4];
  #pragma unroll
  for (int n = 0; n < 4; ++n) bv[n] = bias[bn + wc + n*16 + fr];
  #pragma unroll
  for (int m = 0; m < 4; ++m) {
    #pragma unroll
    for (int r = 0; r < 4; ++r) {
      const int row = bm + wr + m*16 + fg*4 + r;
      #pragma unroll
      for (int n = 0; n < 4; ++n) {
        const int col = bn + wc + n*16 + fr;
        float x = acc[m][n][r] + bv[n];
        if constexpr (EPI == 1) x = b2f(aux[(size_t)row * N + col]) + scale * x;
        if constexpr (EPI == 2) x = 0.5f * x * (1.f + erff(x * 0.70710678118654752f));
        if constexpr (sizeof(TO) == 2) out[(size_t)row * N + col] = f2b(x);
        else                           out[(size_t)row * N + col] = x;
      }
    }
  }
}

// ---------------- attention: one WAVE per row ------------------------------
__device__ __forceinline__ BF8 pack8(float4 a, float4 b){
  BF8 o;
  o.v[0]=f2b(a.x); o.v[1]=f2b(a.y); o.v[2]=f2b(a.z); o.v[3]=f2b(a.w);
  o.v[4]=f2b(b.x); o.v[5]=f2b(b.y); o.v[6]=f2b(b.z); o.v[7]=f2b(b.w);
  return o;
}

__global__ __launch_bounds__(256) void attn_k(
    const bf16* __restrict__ q, const bf16* __restrict__ fn,
    const float* __restrict__ Km, const float* __restrict__ Vm,
    const float* __restrict__ an, const float* __restrict__ na,
    bf16* __restrict__ att, float* __restrict__ cen_acc) {
  __shared__ bf16 Kb[K_][D_];
  __shared__ bf16 Vb[K_][D_];
  __shared__ bf16 Ab[K_][D_];
  __shared__ float na_s[K_];
  __shared__ float cred[4];
  const int t = threadIdx.x;

  for (int i = t * 8; i < K_*D_; i += 2048) {
    float4 k0 = *(const float4*)(Km + i), k1 = *(const float4*)(Km + i + 4);
    float4 v0 = *(const float4*)(Vm + i), v1 = *(const float4*)(Vm + i + 4);
    float4 a0 = *(const float4*)(an + i), a1 = *(const float4*)(an + i + 4);
    *(BF8*)(&Kb[0][0] + i) = pack8(k0, k1);
    *(BF8*)(&Vb[0][0] + i) = pack8(v0, v1);
    *(BF8*)(&Ab[0][0] + i) = pack8(a0, a1);
  }
  if (t < K_) na_s[t] = na[t];
  __syncthreads();

  const int wid = t >> 6, lane = t & 63;
  const int d0 = lane * 16;
  float c_acc = 0.f;
  const int row0 = blockIdx.x * 32 + wid * 8;

  for (int i = 0; i < 8; ++i) {
    const int row = row0 + i;
    const BF8* qr = (const BF8*)(q  + (size_t)row * D_) + lane * 2;
    const BF8* fr = (const BF8*)(fn + (size_t)row * D_) + lane * 2;
    BF8 q0 = qr[0], q1 = qr[1], f0 = fr[0], f1 = fr[1];
    float qv[16], fv[16];
    #pragma unroll
    for (int j = 0; j < 8; ++j) {
      qv[j] = b2f(q0.v[j]); qv[8+j] = b2f(q1.v[j]);
      fv[j] = b2f(f0.v[j]); fv[8+j] = b2f(f1.v[j]);
    }
    float p[K_];
    #pragma unroll
    for (int k = 0; k < K_; ++k) {
      BF8 ka = *(const BF8*)&Kb[k][d0];
      BF8 kb = *(const BF8*)&Kb[k][d0 + 8];
      float s = 0.f;
      #pragma unroll
      for (int j = 0; j < 8; ++j) {
        s = fmaf(qv[j],   b2f(ka.v[j]), s);
        s = fmaf(qv[8+j], b2f(kb.v[j]), s);
      }
      s += __shfl_xor(s, 1); s += __shfl_xor(s, 2); s += __shfl_xor(s, 4);
      p[k] = s * 0.08838834764831845f;
    }
    float m = p[0];
    #pragma unroll
    for (int k = 1; k < K_; ++k) m = fmaxf(m, p[k]);
    float sum = 0.f;
    #pragma unroll
    for (int k = 0; k < K_; ++k) { p[k] = __expf(p[k] - m); sum += p[k]; }
    float inv = 1.f / sum;
    #pragma unroll
    for (int k = 0; k < K_; ++k) p[k] *= inv;
    float ov[16];
    #pragma unroll
    for (int j = 0; j < 16; ++j) ov[j] = 0.f;
    #pragma unroll
    for (int k = 0; k < K_; ++k) {
      BF8 va = *(const BF8*)&Vb[k][d0];
      BF8 vb = *(const BF8*)&Vb[k][d0 + 8];
      #pragma unroll
      for (int j = 0; j < 8; ++j) {
        ov[j]   = fmaf(p[k], b2f(va.v[j]), ov[j]);
        ov[8+j] = fmaf(p[k], b2f(vb.v[j]), ov[8+j]);
      }
    }
    BF8 o0, o1;
    #pragma unroll
    for (int j = 0; j < 8; ++j) { o0.v[j] = f2b(ov[j]); o1.v[j] = f2b(ov[8+j]); }
    BF8* ow = (BF8*)(att + (size_t)row * D_) + lane * 2;
    ow[0] = o0; ow[1] = o1;
    #pragma unroll
    for (int k = 0; k < K_; ++k) {
      BF8 aa = *(const BF8*)&Ab[k][d0];
      BF8 ab = *(const BF8*)&Ab[k][d0 + 8];
      float s = 0.f;
      #pragma unroll
      for (int j = 0; j < 8; ++j) {
        s = fmaf(fv[j],   b2f(aa.v[j]), s);
        s = fmaf(fv[8+j], b2f(ab.v[j]), s);
      }
      #pragma unroll
      for (int o = 1; o < 64; o <<= 1) s += __shfl_xor(s, o);
      float dist = sqrtf(fmaxf(1.f + na_s[k] - 2.f * s, 1e-12f));
      c_acc = fmaf(p[k], dist, c_acc);
    }
  }
  #pragma unroll
  for (int o = 1; o < 64; o <<= 1) c_acc += __shfl_xor(c_acc, o);
  if (lane == 0) cred[wid] = c_acc;
  __syncthreads();
  if (t == 0) {
    float s = (cred[0] + cred[1] + cred[2] + cred[3]) * (1.f / 64.f / (float)B_);
    atomicAdd(cen_acc, s);
  }
}

// ---------------- LayerNorm over rows of bf16 ------------------------------
__global__ __launch_bounds__(256) void ln_k(const bf16* __restrict__ x,
    const float* __restrict__ g, const float* __restrict__ bta,
    bf16* __restrict__ out) {
  int b = blockIdx.x, t = threadIdx.x;
  BF4 ld = ((const BF4*)(x + (size_t)b * D_))[t];
  float v[4];
  #pragma unroll
  for (int j = 0; j < 4; ++j) v[j] = b2f(ld.v[j]);
  float s = v[0]+v[1]+v[2]+v[3];
  #pragma unroll
  for (int o = 32; o > 0; o >>= 1) s += __shfl_down(s, o);
  __shared__ float w1[4], w2[4];
  if ((t & 63) == 0) w1[t >> 6] = s;
  __syncthreads();
  __shared__ float mu_s, rs_s;
  if (t == 0) mu_s = (w1[0]+w1[1]+w1[2]+w1[3]) * (1.f/D_);
  __syncthreads();
  float mu = mu_s;
  float qv = 0.f;
  #pragma unroll
  for (int j = 0; j < 4; ++j) { float d = v[j]-mu; qv += d*d; }
  #pragma unroll
  for (int o = 32; o > 0; o >>= 1) qv += __shfl_down(qv, o);
  if ((t & 63) == 0) w2[t >> 6] = qv;
  __syncthreads();
  if (t == 0) rs_s = rsqrtf((w2[0]+w2[1]+w2[2]+w2[3]) * (1.f/D_) + 1e-5f);
  __syncthreads();
  float rs = rs_s;
  BF4 o;
  #pragma unroll
  for (int j = 0; j < 4; ++j) {
    int col = t*4 + j;
    o.v[j] = f2b((v[j]-mu)*rs*g[col] + bta[col]);
  }
  ((BF4*)(out + (size_t)b * D_))[t] = o;
}

// ---------------- final scalar geo -----------------------------------------
__global__ void geo_k(const float* __restrict__ divl, const float* __restrict__ cen,
                      const float* __restrict__ div_w, const float* __restrict__ cen_w,
                      float* __restrict__ out) {
  float g = fabsf(*div_w) * (*divl) + fabsf(*cen_w) * (*cen);
  out[0] = fminf(fmaxf(g, 0.f), 0.01f);
}

extern "C" void kernel_launch(void* const* d_in, const int* in_sizes, int n_in,
                              void* d_out, int out_size, void* d_ws, size_t ws_size,
                              hipStream_t stream) {
  const float* features = (const float*)d_in[0];
  const float* anchors  = (const float*)d_in[1];
  const float* ar_w1 = (const float*)d_in[2];
  const float* ar_b1 = (const float*)d_in[3];
  const float* ar_w2 = (const float*)d_in[4];
  const float* ar_b2 = (const float*)d_in[5];
  const float* q_w = (const float*)d_in[6];
  const float* q_b = (const float*)d_in[7];
  const float* k_w = (const float*)d_in[8];
  const float* k_b = (const float*)d_in[9];
  const float* v_w = (const float*)d_in[10];
  const float* v_b = (const float*)d_in[11];
  const float* o_w = (const float*)d_in[12];
  const float* o_b = (const float*)d_in[13];
  const float* ln_g = (const float*)d_in[14];
  const float* ln_b = (const float*)d_in[15];
  const float* ff_w1 = (const float*)d_in[16];
  const float* ff_b1 = (const float*)d_in[17];
  const float* ff_w2 = (const float*)d_in[18];
  const float* ff_b2 = (const float*)d_in[19];
  const float* div_w = (const float*)d_in[20];
  const float* cen_w = (const float*)d_in[21];
  float* out = (float*)d_out;

  char* w = (char*)d_ws;
  bf16* ws_fnb = (bf16*)w;  w += (size_t)B_ * D_ * 2;
  bf16* ws_q   = (bf16*)w;  w += (size_t)B_ * D_ * 2;
  bf16* ws_att = (bf16*)w;  w += (size_t)B_ * D_ * 2;
  bf16* ws_h   = (bf16*)w;  w += (size_t)B_ * 2048 * 2;
  bf16* ws_wq  = (bf16*)w;  w += (size_t)D_ * D_ * 2;
  bf16* ws_wo  = (bf16*)w;  w += (size_t)D_ * D_ * 2;
  bf16* ws_w1t = (bf16*)w;  w += (size_t)D_ * 2048 * 2;
  bf16* ws_w2t = (bf16*)w;  w += (size_t)2048 * D_ * 2;
  float* ws_har = (float*)w;  w += (size_t)K_ * (D_/2) * 4;
  float* ws_anu = (float*)w;  w += (size_t)K_ * D_ * 4;
  float* ws_an  = (float*)w;  w += (size_t)K_ * D_ * 4;
  float* ws_k   = (float*)w;  w += (size_t)K_ * D_ * 4;
  float* ws_v   = (float*)w;  w += (size_t)K_ * D_ * 4;
  float* ws_na  = (float*)w;  w += 256;
  float* ws_div = (float*)w;  w += 256;
  float* ws_cen = (float*)w;  w += 256;
  if ((size_t)(w - (char*)d_ws) > ws_size) return;

  hipMemsetAsync(ws_cen, 0, 4, stream);

  wt_k<<<dim3(D_/32,   D_/32),   256, 0, stream>>>(q_w,   ws_wq,  D_,   D_);
  wt_k<<<dim3(D_/32,   D_/32),   256, 0, stream>>>(o_w,   ws_wo,  D_,   D_);
  wt_k<<<dim3(2048/32, D_/32),   256, 0, stream>>>(ff_w1, ws_w1t, D_,   2048);
  wt_k<<<dim3(D_/32,   2048/32), 256, 0, stream>>>(ff_w2, ws_w2t, 2048, D_);

  l2norm_k<<<B_, 256, 0, stream>>>(features, ws_fnb);

  // anchor path: h = relu(anchors@w1+b1)  [16 blocks]
  panelmm_k<32, 1024, 1><<<16, 256, 0, stream>>>(
      anchors, ar_w1, ar_b1, nullptr, ws_har,
      nullptr, nullptr, nullptr, D_/2, 16);
  // an_un = anchors + 0.1*tanh(h@w2+b2)   [16 blocks]
  panelmm_k<64, 512, 2><<<16, 256, 0, stream>>>(
      ws_har, ar_w2, ar_b2, anchors, ws_anu,
      nullptr, nullptr, nullptr, D_, 16);
  // normalize + diversity
  ar3_k<<<1, 256, 0, stream>>>(ws_anu, ws_an, ws_na, ws_div);
  // K = an@k_w+k_b ; V = an@v_w+v_b       [32 blocks]
  panelmm_k<64, 1024, 0><<<32, 256, 0, stream>>>(
      ws_an, k_w, k_b, nullptr, ws_k,
      v_w, v_b, ws_v, D_, 16);

  mgemm_k<0, bf16><<<dim3((B_/128)*(D_/128)), 256, 0, stream>>>(
      ws_fnb, ws_wq, q_b, nullptr, ws_q, B_, D_, D_, 0.f);

  attn_k<<<B_/32, 256, 0, stream>>>(ws_q, ws_fnb, ws_k, ws_v, ws_an, ws_na, ws_att, ws_cen);

  mgemm_k<1, bf16><<<dim3((B_/128)*(D_/128)), 256, 0, stream>>>(
      ws_att, ws_wo, o_b, ws_fnb, ws_q, B_, D_, D_, 0.1f);

  ln_k<<<B_, 256, 0, stream>>>(ws_q, ln_g, ln_b, ws_att);

  mgemm_k<2, bf16><<<dim3((B_/128)*(2048/128)), 256, 0, stream>>>(
      ws_att, ws_w1t, ff_b1, nullptr, ws_h, B_, 2048, D_, 0.f);

  mgemm_k<1, float><<<dim3((B_/128)*(D_/128)), 256, 0, stream>>>(
      ws_h, ws_w2t, ff_b2, ws_fnb, out, B_, D_, 2048, 0.2f);

  geo_k<<<1, 1, 0, stream>>>(ws_div, ws_cen, div_w, cen_w, out + (size_t)B_ * D_);
}

// Round 5
// 475.974 us; speedup vs baseline: 7.3080x; 1.2883x over previous
//
#include <hip/hip_runtime.h>
#include <hip/hip_bf16.h>
#include <math.h>

typedef __hip_bfloat16 bf16;

#define D_  1024
#define K_  10
#define B_  16384
#define H_  8
#define HD_ 128

struct alignas(16) BF8 { bf16 v[8]; };
struct alignas(8)  BF4 { bf16 v[4]; };

typedef __bf16 bf8v __attribute__((ext_vector_type(8)));
typedef float  f4v  __attribute__((ext_vector_type(4)));

__device__ __forceinline__ float b2f(bf16 x){ return __bfloat162float(x); }
__device__ __forceinline__ bf16  f2b(float x){ return __float2bfloat16(x); }

#define GL2LDS16(g, l) __builtin_amdgcn_global_load_lds( \
    (__attribute__((address_space(1))) void*)(g), \
    (__attribute__((address_space(3))) void*)(l), 16, 0, 0)

// ---------------- row-wise L2 normalize -> bf16 ----------------------------
__global__ __launch_bounds__(256) void l2norm_k(const float* __restrict__ x,
                                                bf16* __restrict__ fnb) {
  int b = blockIdx.x, t = threadIdx.x;
  float4 v = ((const float4*)(x + (size_t)b * D_))[t];
  float p = v.x*v.x + v.y*v.y + v.z*v.z + v.w*v.w;
  #pragma unroll
  for (int o = 32; o > 0; o >>= 1) p += __shfl_down(p, o);
  __shared__ float wsum[4];
  if ((t & 63) == 0) wsum[t >> 6] = p;
  __syncthreads();
  __shared__ float inv_s;
  if (t == 0) inv_s = 1.f / fmaxf(sqrtf(wsum[0]+wsum[1]+wsum[2]+wsum[3]), 1e-8f);
  __syncthreads();
  float iv = inv_s;
  BF4 o;
  o.v[0] = f2b(v.x*iv); o.v[1] = f2b(v.y*iv);
  o.v[2] = f2b(v.z*iv); o.v[3] = f2b(v.w*iv);
  ((BF4*)(fnb + (size_t)b * D_))[t] = o;
}

// ---------------- weight transpose f32[R][C] -> bf16[C][R] -----------------
__global__ __launch_bounds__(256) void wt_k(const float* __restrict__ w,
                                            bf16* __restrict__ wt, int R, int C) {
  __shared__ float tle[32][33];
  int c0 = blockIdx.x * 32, r0 = blockIdx.y * 32;
  int tx = threadIdx.x & 31, ty = threadIdx.x >> 5;
  #pragma unroll
  for (int i = 0; i < 32; i += 8)
    tle[ty + i][tx] = w[(size_t)(r0 + ty + i) * C + c0 + tx];
  __syncthreads();
  #pragma unroll
  for (int i = 0; i < 32; i += 8)
    wt[(size_t)(c0 + ty + i) * R + r0 + tx] = f2b(tle[tx][ty + i]);
}

// ---------------- small panel GEMM: out[10][N] = act(A[10][KD] @ W + b) ----
template<int COLS, int KD, int ACT>
__global__ __launch_bounds__(256) void panelmm_k(
    const float* __restrict__ A, const float* __restrict__ W,
    const float* __restrict__ bias, const float* __restrict__ aux,
    float* __restrict__ out,
    const float* __restrict__ W2, const float* __restrict__ bias2,
    float* __restrict__ out2, int N, int npanel) {
  constexpr int GROUPS = 256 / COLS;
  constexpr int DCH = KD / GROUPS;
  __shared__ float A_s[K_][KD];
  __shared__ float part[K_][COLS][GROUPS];
  const int t = threadIdx.x;
  int blk = blockIdx.x;
  const float* Wm = W; const float* bm = bias; float* om = out;
  if (blk >= npanel) { blk -= npanel; Wm = W2; bm = bias2; om = out2; }
  const int panel = blk;
  for (int i = t; i < K_*KD; i += 256) A_s[0][i] = A[i];
  __syncthreads();
  const int cg = t % COLS, g = t / COLS;
  const int col = panel*COLS + cg;
  float s[K_];
  #pragma unroll
  for (int r = 0; r < K_; ++r) s[r] = 0.f;
  const float* wp = Wm + (size_t)(g*DCH)*N + col;
  for (int d = g*DCH; d < (g+1)*DCH; ++d) {
    float wv = *wp; wp += N;
    #pragma unroll
    for (int r = 0; r < K_; ++r) s[r] = fmaf(A_s[r][d], wv, s[r]);
  }
  #pragma unroll
  for (int r = 0; r < K_; ++r) part[r][cg][g] = s[r];
  __syncthreads();
  for (int o = t; o < K_*COLS; o += 256) {
    int r = o / COLS, c = o % COLS;
    float v = 0.f;
    #pragma unroll
    for (int gg = 0; gg < GROUPS; ++gg) v += part[r][c][gg];
    v += bm[panel*COLS + c];
    if constexpr (ACT == 1) v = fmaxf(v, 0.f);
    if constexpr (ACT == 2) v = aux[(size_t)r*N + panel*COLS + c] + 0.1f*tanhf(v);
    om[(size_t)r*N + panel*COLS + c] = v;
  }
}

// ---------------- small mixed GEMM for W-tilde / V-tilde -------------------
// out = scale * (A_h[10,128] @ W[h*128.., 1024]);  16 rows/head (pads zero)
// TRANSOUT 0: out[(h*16+r)][col] (128 x 1024) ; 1: out[col][(h*16+r)] (1024 x 128)
template<int TRANSOUT, typename TW>
__global__ __launch_bounds__(256) void smallmm_k(
    const float* __restrict__ A, const TW* __restrict__ W,
    bf16* __restrict__ outb, float scale) {
  constexpr int COLS = 64, GROUPS = 4, DCH = 32, NW = 1024;
  __shared__ float A_s[K_][128];
  __shared__ float part[K_][COLS][GROUPS];
  const int t = threadIdx.x;
  const int h = blockIdx.x & 7, panel = blockIdx.x >> 3;
  for (int i = t; i < K_*128; i += 256) {
    int r = i >> 7, j = i & 127;
    A_s[r][j] = A[r*1024 + h*128 + j];
  }
  __syncthreads();
  const int cg = t % COLS, g = t / COLS;
  const int col = panel*COLS + cg;
  float s[K_];
  #pragma unroll
  for (int r = 0; r < K_; ++r) s[r] = 0.f;
  const TW* wp = W + (size_t)(h*128 + g*DCH)*NW + col;
  for (int d = g*DCH; d < g*DCH + DCH; ++d) {
    float wv;
    if constexpr (sizeof(TW) == 2) wv = b2f(*wp); else wv = *wp;
    wp += NW;
    #pragma unroll
    for (int r = 0; r < K_; ++r) s[r] = fmaf(A_s[r][d], wv, s[r]);
  }
  #pragma unroll
  for (int r = 0; r < K_; ++r) part[r][cg][g] = s[r];
  __syncthreads();
  for (int o = t; o < 16*COLS; o += 256) {
    int r = o / COLS, c = o % COLS;
    float v = 0.f;
    if (r < K_) {
      #pragma unroll
      for (int gg = 0; gg < GROUPS; ++gg) v += part[r][c][gg];
      v *= scale;
    }
    if constexpr (TRANSOUT) outb[(size_t)(panel*COLS + c)*128 + h*16 + r] = f2b(v);
    else                    outb[(size_t)(h*16 + r)*NW + panel*COLS + c] = f2b(v);
  }
}

// ---------------- S-bias: sb[h*16+k] = (q_b_h . K_hk) / sqrt(128) ----------
__global__ void sbias_k(const float* __restrict__ qb, const float* __restrict__ Km,
                        float* __restrict__ sb) {
  int c = threadIdx.x;
  int h = c >> 4, k = c & 15;
  float s = 0.f;
  if (k < K_) {
    for (int j = 0; j < HD_; ++j)
      s = fmaf(qb[h*HD_ + j], Km[(size_t)k*D_ + h*HD_ + j], s);
  }
  sb[c] = s * 0.08838834764831845f;
}

// ---------------- ar3: normalize anchors + diversity loss ------------------
__global__ __launch_bounds__(256) void ar3_k(const float* __restrict__ an_un,
    float* __restrict__ an, float* __restrict__ na, float* __restrict__ divloss) {
  __shared__ float a_s[K_][D_];
  __shared__ float nrm[K_];
  __shared__ float dm[45];
  const int t = threadIdx.x;
  for (int i = t; i < K_*D_; i += 256) a_s[0][i] = an_un[i];
  __syncthreads();
  const int wid = t >> 6, lane = t & 63;
  for (int r = wid; r < K_; r += 4) {
    float p = 0.f;
    for (int j = lane; j < D_; j += 64) p += a_s[r][j]*a_s[r][j];
    #pragma unroll
    for (int o = 1; o < 64; o <<= 1) p += __shfl_xor(p, o);
    if (lane == 0) nrm[r] = p;
  }
  __syncthreads();
  for (int i = t; i < K_*D_; i += 256) {
    int r = i >> 10;
    float iv = 1.f / fmaxf(sqrtf(nrm[r]), 1e-8f);
    float v = a_s[0][i] * iv;
    a_s[0][i] = v;
    an[i] = v;
  }
  if (t < K_) {
    float iv = 1.f / fmaxf(sqrtf(nrm[t]), 1e-8f);
    na[t] = nrm[t] * iv * iv;
  }
  __syncthreads();
  const int pr = t >> 2, sub = t & 3;
  if (pr < 45) {
    int i = 0, j = 0, c = pr;
    for (i = 0; i < K_; ++i) { int cnt = K_-1-i; if (c < cnt) { j = i+1+c; break; } c -= cnt; }
    float s = 0.f;
    for (int d = sub*256; d < sub*256 + 256; ++d) {
      float df = a_s[i][d] - a_s[j][d]; s += df*df;
    }
    s += __shfl_xor(s, 1); s += __shfl_xor(s, 2);
    if (sub == 0) dm[pr] = sqrtf(fmaxf(s, 1e-24f));
  }
  __syncthreads();
  if (t == 0) {
    float m = 0.f;
    for (int p = 0; p < 45; ++p) m += dm[p];
    m *= (1.f/45.f);
    *divloss = expf(-fmaxf(m, 1e-6f));
  }
}

// ---------------- MFMA GEMM: C[M,N] = epi(A[M,K] @ Bt[N,K]^T + bias) -------
template<int EPI, typename TO>
__global__ __launch_bounds__(256) void mgemm_k(
    const bf16* __restrict__ A, const bf16* __restrict__ Bt,
    const float* __restrict__ bias, const bf16* __restrict__ aux,
    TO* __restrict__ out, int M, int N, int Kd, float scale) {
  constexpr int BM = 128, BN = 128, BK = 32;
  __shared__ bf16 As[BM][BK];
  __shared__ bf16 Bs[BN][BK];
  const int tid = threadIdx.x;
  const int nMB = M / BM;
  const int nwg = gridDim.x;
  int wg = blockIdx.x;
  wg = (wg & 7) * (nwg >> 3) + (wg >> 3);
  const int mb = wg % nMB, nb = wg / nMB;
  const int bm = mb * BM, bn = nb * BN;

  const int srow = tid >> 2;
  const int sk   = (tid & 3) * 8;
  const bf16* ga = A  + (size_t)(bm + srow) * Kd + sk;
  const bf16* gb = Bt + (size_t)(bn + srow) * Kd + sk;
  const size_t rstep = (size_t)64 * Kd;
  bf16* la = &As[0][0] + tid * 8;
  bf16* lb = &Bs[0][0] + tid * 8;

  const int w    = tid >> 6;
  const int lane = tid & 63;
  const int wr = (w >> 1) * 64, wc = (w & 1) * 64;
  const int fr = lane & 15, fg = lane >> 4;

  f4v acc[4][4];
  const f4v zz = {0.f, 0.f, 0.f, 0.f};
  #pragma unroll
  for (int m = 0; m < 4; ++m)
    #pragma unroll
    for (int n = 0; n < 4; ++n) acc[m][n] = zz;

  for (int k0 = 0; k0 < Kd; k0 += BK) {
    GL2LDS16(ga,         la);
    GL2LDS16(ga + rstep, la + 2048);
    GL2LDS16(gb,         lb);
    GL2LDS16(gb + rstep, lb + 2048);
    __syncthreads();
    bf8v af[4], bf_[4];
    #pragma unroll
    for (int m = 0; m < 4; ++m)
      af[m] = *(const bf8v*)&As[wr + m*16 + fr][fg*8];
    #pragma unroll
    for (int n = 0; n < 4; ++n)
      bf_[n] = *(const bf8v*)&Bs[wc + n*16 + fr][fg*8];
    #pragma unroll
    for (int m = 0; m < 4; ++m)
      #pragma unroll
      for (int n = 0; n < 4; ++n)
        acc[m][n] = __builtin_amdgcn_mfma_f32_16x16x32_bf16(af[m], bf_[n], acc[m][n], 0, 0, 0);
    __syncthreads();
    ga += BK; gb += BK;
  }

  float bv[4];
  #pragma unroll
  for (int n = 0; n < 4; ++n) bv[n] = bias[bn + wc + n*16 + fr];
  #pragma unroll
  for (int m = 0; m < 4; ++m) {
    #pragma unroll
    for (int r = 0; r < 4; ++r) {
      const int row = bm + wr + m*16 + fg*4 + r;
      #pragma unroll
      for (int n = 0; n < 4; ++n) {
        const int col = bn + wc + n*16 + fr;
        float x = acc[m][n][r] + bv[n];
        if constexpr (EPI == 1) x = b2f(aux[(size_t)row * N + col]) + scale * x;
        if constexpr (EPI == 2) x = 0.5f * x * (1.f + erff(x * 0.70710678118654752f));
        if constexpr (sizeof(TO) == 2) out[(size_t)row * N + col] = f2b(x);
        else                           out[(size_t)row * N + col] = x;
      }
    }
  }
}

__device__ __forceinline__ BF8 pack8(float4 a, float4 b){
  BF8 o;
  o.v[0]=f2b(a.x); o.v[1]=f2b(a.y); o.v[2]=f2b(a.z); o.v[3]=f2b(a.w);
  o.v[4]=f2b(b.x); o.v[5]=f2b(b.y); o.v[6]=f2b(b.z); o.v[7]=f2b(b.w);
  return o;
}

// ---------------- attn2: softmax(S) -> aw, center loss ---------------------
// block = 256 thr (4 waves), 8 rows/wave; grid = B/32
__global__ __launch_bounds__(256) void attn2_k(
    const float* __restrict__ S, const bf16* __restrict__ fn,
    const float* __restrict__ an, const float* __restrict__ na,
    bf16* __restrict__ awp, float* __restrict__ cen_acc) {
  __shared__ bf16 Ab[K_][D_];
  __shared__ float na_s[K_];
  __shared__ float cred[4];
  const int t = threadIdx.x;
  for (int i = t*8; i < K_*D_; i += 2048) {
    float4 a0 = *(const float4*)(an+i), a1 = *(const float4*)(an+i+4);
    *(BF8*)(&Ab[0][0]+i) = pack8(a0, a1);
  }
  if (t < K_) na_s[t] = na[t];
  __syncthreads();
  const int wid = t >> 6, lane = t & 63;
  const int d0 = lane * 16;
  const int sub = lane & 7, head = lane >> 3;
  const int k0 = sub*2, k1 = k0 + 1;
  float na0 = (k0 < K_) ? na_s[k0] : 0.f;
  float na1 = (k1 < K_) ? na_s[k1] : 0.f;
  float c_acc = 0.f;
  const int row0 = blockIdx.x * 32 + wid * 8;

  for (int i = 0; i < 8; ++i) {
    const int row = row0 + i;
    float2 sv = *(const float2*)(S + (size_t)row*128 + head*16 + k0);
    float v0 = (k0 < K_) ? sv.x : -1e30f;
    float v1 = (k1 < K_) ? sv.y : -1e30f;
    float m = fmaxf(v0, v1);
    m = fmaxf(m, __shfl_xor(m,1)); m = fmaxf(m, __shfl_xor(m,2)); m = fmaxf(m, __shfl_xor(m,4));
    float e0 = (k0 < K_) ? __expf(v0 - m) : 0.f;
    float e1 = (k1 < K_) ? __expf(v1 - m) : 0.f;
    float es = e0 + e1;
    es += __shfl_xor(es,1); es += __shfl_xor(es,2); es += __shfl_xor(es,4);
    float inv = 1.f / es;
    float a0 = e0 * inv, a1 = e1 * inv;
    bf16 b0 = f2b(a0), b1 = f2b(a1);
    unsigned int pk = (unsigned int)(*(unsigned short*)&b0)
                    | ((unsigned int)(*(unsigned short*)&b1) << 16);
    *(unsigned int*)(awp + (size_t)row*128 + head*16 + k0) = pk;
    // sum over heads (lane bits 3..5)
    float g0 = a0, g1 = a1;
    g0 += __shfl_xor(g0,8); g0 += __shfl_xor(g0,16); g0 += __shfl_xor(g0,32);
    g1 += __shfl_xor(g1,8); g1 += __shfl_xor(g1,16); g1 += __shfl_xor(g1,32);
    // fn . an_k  (wave-wide, 16 dims per lane)
    const BF8* fr = (const BF8*)(fn + (size_t)row*D_) + lane*2;
    BF8 f0 = fr[0], f1 = fr[1];
    float fv[16];
    #pragma unroll
    for (int j = 0; j < 8; ++j) { fv[j] = b2f(f0.v[j]); fv[8+j] = b2f(f1.v[j]); }
    float my0 = 0.f, my1 = 0.f;
    #pragma unroll
    for (int k = 0; k < K_; ++k) {
      BF8 aa = *(const BF8*)&Ab[k][d0];
      BF8 ab = *(const BF8*)&Ab[k][d0 + 8];
      float s = 0.f;
      #pragma unroll
      for (int j = 0; j < 8; ++j) {
        s = fmaf(fv[j],   b2f(aa.v[j]), s);
        s = fmaf(fv[8+j], b2f(ab.v[j]), s);
      }
      #pragma unroll
      for (int o = 1; o < 64; o <<= 1) s += __shfl_xor(s, o);
      my0 = (k == k0) ? s : my0;
      my1 = (k == k1) ? s : my1;
    }
    if (sub < 5) {
      float dist0 = sqrtf(fmaxf(1.f + na0 - 2.f*my0, 1e-12f));
      float dist1 = sqrtf(fmaxf(1.f + na1 - 2.f*my1, 1e-12f));
      c_acc = fmaf(g0, dist0, c_acc);
      c_acc = fmaf(g1, dist1, c_acc);
    }
  }
  #pragma unroll
  for (int o = 1; o < 64; o <<= 1) c_acc += __shfl_xor(c_acc, o);
  if (lane == 0) cred[wid] = c_acc;
  __syncthreads();
  if (t == 0) {
    float s = (cred[0]+cred[1]+cred[2]+cred[3]) * (1.f/64.f/(float)B_);
    atomicAdd(cen_acc, s);
  }
}

// ---------------- LayerNorm over rows of bf16 ------------------------------
__global__ __launch_bounds__(256) void ln_k(const bf16* __restrict__ x,
    const float* __restrict__ g, const float* __restrict__ bta,
    bf16* __restrict__ out) {
  int b = blockIdx.x, t = threadIdx.x;
  BF4 ld = ((const BF4*)(x + (size_t)b * D_))[t];
  float v[4];
  #pragma unroll
  for (int j = 0; j < 4; ++j) v[j] = b2f(ld.v[j]);
  float s = v[0]+v[1]+v[2]+v[3];
  #pragma unroll
  for (int o = 32; o > 0; o >>= 1) s += __shfl_down(s, o);
  __shared__ float w1[4], w2[4];
  if ((t & 63) == 0) w1[t >> 6] = s;
  __syncthreads();
  __shared__ float mu_s, rs_s;
  if (t == 0) mu_s = (w1[0]+w1[1]+w1[2]+w1[3]) * (1.f/D_);
  __syncthreads();
  float mu = mu_s;
  float qv = 0.f;
  #pragma unroll
  for (int j = 0; j < 4; ++j) { float d = v[j]-mu; qv += d*d; }
  #pragma unroll
  for (int o = 32; o > 0; o >>= 1) qv += __shfl_down(qv, o);
  if ((t & 63) == 0) w2[t >> 6] = qv;
  __syncthreads();
  if (t == 0) rs_s = rsqrtf((w2[0]+w2[1]+w2[2]+w2[3]) * (1.f/D_) + 1e-5f);
  __syncthreads();
  float rs = rs_s;
  BF4 o;
  #pragma unroll
  for (int j = 0; j < 4; ++j) {
    int col = t*4 + j;
    o.v[j] = f2b((v[j]-mu)*rs*g[col] + bta[col]);
  }
  ((BF4*)(out + (size_t)b * D_))[t] = o;
}

// ---------------- final scalar geo -----------------------------------------
__global__ void geo_k(const float* __restrict__ divl, const float* __restrict__ cen,
                      const float* __restrict__ div_w, const float* __restrict__ cen_w,
                      float* __restrict__ out) {
  float g = fabsf(*div_w) * (*divl) + fabsf(*cen_w) * (*cen);
  out[0] = fminf(fmaxf(g, 0.f), 0.01f);
}

extern "C" void kernel_launch(void* const* d_in, const int* in_sizes, int n_in,
                              void* d_out, int out_size, void* d_ws, size_t ws_size,
                              hipStream_t stream) {
  const float* features = (const float*)d_in[0];
  const float* anchors  = (const float*)d_in[1];
  const float* ar_w1 = (const float*)d_in[2];
  const float* ar_b1 = (const float*)d_in[3];
  const float* ar_w2 = (const float*)d_in[4];
  const float* ar_b2 = (const float*)d_in[5];
  const float* q_w = (const float*)d_in[6];
  const float* q_b = (const float*)d_in[7];
  const float* k_w = (const float*)d_in[8];
  const float* k_b = (const float*)d_in[9];
  const float* v_w = (const float*)d_in[10];
  const float* v_b = (const float*)d_in[11];
  const float* o_w = (const float*)d_in[12];
  const float* o_b = (const float*)d_in[13];
  const float* ln_g = (const float*)d_in[14];
  const float* ln_b = (const float*)d_in[15];
  const float* ff_w1 = (const float*)d_in[16];
  const float* ff_b1 = (const float*)d_in[17];
  const float* ff_w2 = (const float*)d_in[18];
  const float* ff_b2 = (const float*)d_in[19];
  const float* div_w = (const float*)d_in[20];
  const float* cen_w = (const float*)d_in[21];
  float* out = (float*)d_out;

  char* w = (char*)d_ws;
  bf16* ws_fnb = (bf16*)w;  w += (size_t)B_ * D_ * 2;
  bf16* ws_enh = (bf16*)w;  w += (size_t)B_ * D_ * 2;
  bf16* ws_ln  = (bf16*)w;  w += (size_t)B_ * D_ * 2;
  bf16* ws_h   = (bf16*)w;  w += (size_t)B_ * 2048 * 2;
  float* ws_S  = (float*)w; w += (size_t)B_ * 128 * 4;
  bf16* ws_awp = (bf16*)w;  w += (size_t)B_ * 128 * 2;
  bf16* ws_wq  = (bf16*)w;  w += (size_t)D_ * D_ * 2;
  bf16* ws_w1t = (bf16*)w;  w += (size_t)D_ * 2048 * 2;
  bf16* ws_w2t = (bf16*)w;  w += (size_t)2048 * D_ * 2;
  bf16* ws_wt  = (bf16*)w;  w += (size_t)128 * D_ * 2;   // W-tilde^T [128][1024]
  bf16* ws_vt  = (bf16*)w;  w += (size_t)D_ * 128 * 2;   // V-tilde^T [1024][128]
  float* ws_har = (float*)w;  w += (size_t)K_ * (D_/2) * 4;
  float* ws_anu = (float*)w;  w += (size_t)K_ * D_ * 4;
  float* ws_an  = (float*)w;  w += (size_t)K_ * D_ * 4;
  float* ws_k   = (float*)w;  w += (size_t)K_ * D_ * 4;
  float* ws_v   = (float*)w;  w += (size_t)K_ * D_ * 4;
  float* ws_na  = (float*)w;  w += 256;
  float* ws_div = (float*)w;  w += 256;
  float* ws_cen = (float*)w;  w += 256;
  float* ws_sb  = (float*)w;  w += 512;
  if ((size_t)(w - (char*)d_ws) > ws_size) return;

  hipMemsetAsync(ws_cen, 0, 4, stream);

  // weight transposes (f32 [K,N] -> bf16 [N,K])
  wt_k<<<dim3(D_/32,   D_/32),   256, 0, stream>>>(q_w,   ws_wq,  D_,   D_);
  wt_k<<<dim3(2048/32, D_/32),   256, 0, stream>>>(ff_w1, ws_w1t, D_,   2048);
  wt_k<<<dim3(D_/32,   2048/32), 256, 0, stream>>>(ff_w2, ws_w2t, 2048, D_);

  l2norm_k<<<B_, 256, 0, stream>>>(features, ws_fnb);

  // anchor path
  panelmm_k<32, 1024, 1><<<16, 256, 0, stream>>>(
      anchors, ar_w1, ar_b1, nullptr, ws_har,
      nullptr, nullptr, nullptr, D_/2, 16);
  panelmm_k<64, 512, 2><<<16, 256, 0, stream>>>(
      ws_har, ar_w2, ar_b2, anchors, ws_anu,
      nullptr, nullptr, nullptr, D_, 16);
  ar3_k<<<1, 256, 0, stream>>>(ws_anu, ws_an, ws_na, ws_div);
  panelmm_k<64, 1024, 0><<<32, 256, 0, stream>>>(
      ws_an, k_w, k_b, nullptr, ws_k,
      v_w, v_b, ws_v, D_, 16);

  // W-tilde^T[hk][d] = (1/sqrt(128)) * sum_j K[k,hj] * q_w[d,hj]
  smallmm_k<0, bf16><<<128, 256, 0, stream>>>(ws_k, ws_wq, ws_wt, 0.08838834764831845f);
  // S bias
  sbias_k<<<1, 128, 0, stream>>>(q_b, ws_k, ws_sb);
  // V-tilde^T[n][hk] = sum_j V[k,hj] * o_w[hj,n]
  smallmm_k<1, float><<<128, 256, 0, stream>>>(ws_v, o_w, ws_vt, 1.f);

  // S = fn @ W-tilde + sb   [B,128] f32
  mgemm_k<0, float><<<dim3((B_/128)*(128/128)), 256, 0, stream>>>(
      ws_fnb, ws_wt, ws_sb, nullptr, ws_S, B_, 128, D_, 0.f);

  // softmax + center loss -> awp [B,128] bf16
  attn2_k<<<B_/32, 256, 0, stream>>>(ws_S, ws_fnb, ws_an, ws_na, ws_awp, ws_cen);

  // enh = fn + 0.1*(awp @ V-tilde + o_b)
  mgemm_k<1, bf16><<<dim3((B_/128)*(D_/128)), 256, 0, stream>>>(
      ws_awp, ws_vt, o_b, ws_fnb, ws_enh, B_, D_, 128, 0.1f);

  // ln = layernorm(enh)
  ln_k<<<B_, 256, 0, stream>>>(ws_enh, ln_g, ln_b, ws_ln);

  // h = gelu(ln @ ff_w1 + ff_b1)
  mgemm_k<2, bf16><<<dim3((B_/128)*(2048/128)), 256, 0, stream>>>(
      ws_ln, ws_w1t, ff_b1, nullptr, ws_h, B_, 2048, D_, 0.f);

  // final = fn + 0.2*(h @ ff_w2 + ff_b2) -> d_out (f32)
  mgemm_k<1, float><<<dim3((B_/128)*(D_/128)), 256, 0, stream>>>(
      ws_h, ws_w2t, ff_b2, ws_fnb, out, B_, D_, 2048, 0.2f);

  geo_k<<<1, 1, 0, stream>>>(ws_div, ws_cen, div_w, cen_w, out + (size_t)B_ * D_);
}

// Round 6
// 446.083 us; speedup vs baseline: 7.7976x; 1.0670x over previous
//
#include <hip/hip_runtime.h>
#include <hip/hip_bf16.h>
#include <math.h>

typedef __hip_bfloat16 bf16;

#define D_  1024
#define K_  10
#define B_  16384
#define H_  8
#define HD_ 128

struct alignas(16) BF8 { bf16 v[8]; };
struct alignas(8)  BF4 { bf16 v[4]; };

typedef __bf16 bf8v __attribute__((ext_vector_type(8)));
typedef float  f4v  __attribute__((ext_vector_type(4)));

__device__ __forceinline__ float b2f(bf16 x){ return __bfloat162float(x); }
__device__ __forceinline__ bf16  f2b(float x){ return __float2bfloat16(x); }

#define GL2LDS16(g, l) __builtin_amdgcn_global_load_lds( \
    (__attribute__((address_space(1))) void*)(g), \
    (__attribute__((address_space(3))) void*)(l), 16, 0, 0)

// ---------------- row-wise L2 normalize -> bf16 ----------------------------
__global__ __launch_bounds__(256) void l2norm_k(const float* __restrict__ x,
                                                bf16* __restrict__ fnb) {
  int b = blockIdx.x, t = threadIdx.x;
  float4 v = ((const float4*)(x + (size_t)b * D_))[t];
  float p = v.x*v.x + v.y*v.y + v.z*v.z + v.w*v.w;
  #pragma unroll
  for (int o = 32; o > 0; o >>= 1) p += __shfl_down(p, o);
  __shared__ float wsum[4];
  if ((t & 63) == 0) wsum[t >> 6] = p;
  __syncthreads();
  __shared__ float inv_s;
  if (t == 0) inv_s = 1.f / fmaxf(sqrtf(wsum[0]+wsum[1]+wsum[2]+wsum[3]), 1e-8f);
  __syncthreads();
  float iv = inv_s;
  BF4 o;
  o.v[0] = f2b(v.x*iv); o.v[1] = f2b(v.y*iv);
  o.v[2] = f2b(v.z*iv); o.v[3] = f2b(v.w*iv);
  ((BF4*)(fnb + (size_t)b * D_))[t] = o;
}

// ---------------- weight transpose f32[R][C] -> bf16[C][R] -----------------
__global__ __launch_bounds__(256) void wt_k(const float* __restrict__ w,
                                            bf16* __restrict__ wt, int R, int C) {
  __shared__ float tle[32][33];
  int c0 = blockIdx.x * 32, r0 = blockIdx.y * 32;
  int tx = threadIdx.x & 31, ty = threadIdx.x >> 5;
  #pragma unroll
  for (int i = 0; i < 32; i += 8)
    tle[ty + i][tx] = w[(size_t)(r0 + ty + i) * C + c0 + tx];
  __syncthreads();
  #pragma unroll
  for (int i = 0; i < 32; i += 8)
    wt[(size_t)(c0 + ty + i) * R + r0 + tx] = f2b(tle[tx][ty + i]);
}

// ---------------- small panel GEMM: out[10][N] = act(A[10][KD] @ W + b) ----
template<int COLS, int KD, int ACT>
__global__ __launch_bounds__(256) void panelmm_k(
    const float* __restrict__ A, const float* __restrict__ W,
    const float* __restrict__ bias, const float* __restrict__ aux,
    float* __restrict__ out,
    const float* __restrict__ W2, const float* __restrict__ bias2,
    float* __restrict__ out2, int N, int npanel) {
  constexpr int GROUPS = 256 / COLS;
  constexpr int DCH = KD / GROUPS;
  __shared__ float A_s[K_][KD];
  __shared__ float part[K_][COLS][GROUPS];
  const int t = threadIdx.x;
  int blk = blockIdx.x;
  const float* Wm = W; const float* bm = bias; float* om = out;
  if (blk >= npanel) { blk -= npanel; Wm = W2; bm = bias2; om = out2; }
  const int panel = blk;
  for (int i = t; i < K_*KD; i += 256) A_s[0][i] = A[i];
  __syncthreads();
  const int cg = t % COLS, g = t / COLS;
  const int col = panel*COLS + cg;
  float s[K_];
  #pragma unroll
  for (int r = 0; r < K_; ++r) s[r] = 0.f;
  const float* wp = Wm + (size_t)(g*DCH)*N + col;
  for (int d = g*DCH; d < (g+1)*DCH; ++d) {
    float wv = *wp; wp += N;
    #pragma unroll
    for (int r = 0; r < K_; ++r) s[r] = fmaf(A_s[r][d], wv, s[r]);
  }
  #pragma unroll
  for (int r = 0; r < K_; ++r) part[r][cg][g] = s[r];
  __syncthreads();
  for (int o = t; o < K_*COLS; o += 256) {
    int r = o / COLS, c = o % COLS;
    float v = 0.f;
    #pragma unroll
    for (int gg = 0; gg < GROUPS; ++gg) v += part[r][c][gg];
    v += bm[panel*COLS + c];
    if constexpr (ACT == 1) v = fmaxf(v, 0.f);
    if constexpr (ACT == 2) v = aux[(size_t)r*N + panel*COLS + c] + 0.1f*tanhf(v);
    om[(size_t)r*N + panel*COLS + c] = v;
  }
}

// ---------------- small mixed GEMM for W-tilde / V-tilde -------------------
template<int TRANSOUT, typename TW>
__global__ __launch_bounds__(256) void smallmm_k(
    const float* __restrict__ A, const TW* __restrict__ W,
    bf16* __restrict__ outb, float scale) {
  constexpr int COLS = 64, GROUPS = 4, DCH = 32, NW = 1024;
  __shared__ float A_s[K_][128];
  __shared__ float part[K_][COLS][GROUPS];
  const int t = threadIdx.x;
  const int h = blockIdx.x & 7, panel = blockIdx.x >> 3;
  for (int i = t; i < K_*128; i += 256) {
    int r = i >> 7, j = i & 127;
    A_s[r][j] = A[r*1024 + h*128 + j];
  }
  __syncthreads();
  const int cg = t % COLS, g = t / COLS;
  const int col = panel*COLS + cg;
  float s[K_];
  #pragma unroll
  for (int r = 0; r < K_; ++r) s[r] = 0.f;
  const TW* wp = W + (size_t)(h*128 + g*DCH)*NW + col;
  for (int d = g*DCH; d < g*DCH + DCH; ++d) {
    float wv;
    if constexpr (sizeof(TW) == 2) wv = b2f(*wp); else wv = *wp;
    wp += NW;
    #pragma unroll
    for (int r = 0; r < K_; ++r) s[r] = fmaf(A_s[r][d], wv, s[r]);
  }
  #pragma unroll
  for (int r = 0; r < K_; ++r) part[r][cg][g] = s[r];
  __syncthreads();
  for (int o = t; o < 16*COLS; o += 256) {
    int r = o / COLS, c = o % COLS;
    float v = 0.f;
    if (r < K_) {
      #pragma unroll
      for (int gg = 0; gg < GROUPS; ++gg) v += part[r][c][gg];
      v *= scale;
    }
    if constexpr (TRANSOUT) outb[(size_t)(panel*COLS + c)*128 + h*16 + r] = f2b(v);
    else                    outb[(size_t)(h*16 + r)*NW + panel*COLS + c] = f2b(v);
  }
}

// ---------------- S-bias: sb[h*16+k] = (q_b_h . K_hk) / sqrt(128) ----------
__global__ void sbias_k(const float* __restrict__ qb, const float* __restrict__ Km,
                        float* __restrict__ sb) {
  int c = threadIdx.x;
  int h = c >> 4, k = c & 15;
  float s = 0.f;
  if (k < K_) {
    for (int j = 0; j < HD_; ++j)
      s = fmaf(qb[h*HD_ + j], Km[(size_t)k*D_ + h*HD_ + j], s);
  }
  sb[c] = s * 0.08838834764831845f;
}

// ---------------- ar3: normalize anchors + diversity loss ------------------
__global__ __launch_bounds__(256) void ar3_k(const float* __restrict__ an_un,
    float* __restrict__ an, float* __restrict__ na, float* __restrict__ divloss) {
  __shared__ float a_s[K_][D_];
  __shared__ float nrm[K_];
  __shared__ float dm[45];
  const int t = threadIdx.x;
  for (int i = t; i < K_*D_; i += 256) a_s[0][i] = an_un[i];
  __syncthreads();
  const int wid = t >> 6, lane = t & 63;
  for (int r = wid; r < K_; r += 4) {
    float p = 0.f;
    for (int j = lane; j < D_; j += 64) p += a_s[r][j]*a_s[r][j];
    #pragma unroll
    for (int o = 1; o < 64; o <<= 1) p += __shfl_xor(p, o);
    if (lane == 0) nrm[r] = p;
  }
  __syncthreads();
  for (int i = t; i < K_*D_; i += 256) {
    int r = i >> 10;
    float iv = 1.f / fmaxf(sqrtf(nrm[r]), 1e-8f);
    float v = a_s[0][i] * iv;
    a_s[0][i] = v;
    an[i] = v;
  }
  if (t < K_) {
    float iv = 1.f / fmaxf(sqrtf(nrm[t]), 1e-8f);
    na[t] = nrm[t] * iv * iv;
  }
  __syncthreads();
  const int pr = t >> 2, sub = t & 3;
  if (pr < 45) {
    int i = 0, j = 0, c = pr;
    for (i = 0; i < K_; ++i) { int cnt = K_-1-i; if (c < cnt) { j = i+1+c; break; } c -= cnt; }
    float s = 0.f;
    for (int d = sub*256; d < sub*256 + 256; ++d) {
      float df = a_s[i][d] - a_s[j][d]; s += df*df;
    }
    s += __shfl_xor(s, 1); s += __shfl_xor(s, 2);
    if (sub == 0) dm[pr] = sqrtf(fmaxf(s, 1e-24f));
  }
  __syncthreads();
  if (t == 0) {
    float m = 0.f;
    for (int p = 0; p < 45; ++p) m += dm[p];
    m *= (1.f/45.f);
    *divloss = expf(-fmaxf(m, 1e-6f));
  }
}

// ---------------- 128^2 MFMA GEMM (kept for N=128 skinny S-GEMM) -----------
template<int EPI, typename TO>
__global__ __launch_bounds__(256) void mgemm_k(
    const bf16* __restrict__ A, const bf16* __restrict__ Bt,
    const float* __restrict__ bias, const bf16* __restrict__ aux,
    TO* __restrict__ out, int M, int N, int Kd, float scale) {
  constexpr int BM = 128, BN = 128, BK = 32;
  __shared__ bf16 As[BM][BK];
  __shared__ bf16 Bs[BN][BK];
  const int tid = threadIdx.x;
  const int nMB = M / BM;
  const int nwg = gridDim.x;
  int wg = blockIdx.x;
  wg = (wg & 7) * (nwg >> 3) + (wg >> 3);
  const int mb = wg % nMB, nb = wg / nMB;
  const int bm = mb * BM, bn = nb * BN;

  const int srow = tid >> 2;
  const int sk   = (tid & 3) * 8;
  const bf16* ga = A  + (size_t)(bm + srow) * Kd + sk;
  const bf16* gb = Bt + (size_t)(bn + srow) * Kd + sk;
  const size_t rstep = (size_t)64 * Kd;
  bf16* la = &As[0][0] + tid * 8;
  bf16* lb = &Bs[0][0] + tid * 8;

  const int w    = tid >> 6;
  const int lane = tid & 63;
  const int wr = (w >> 1) * 64, wc = (w & 1) * 64;
  const int fr = lane & 15, fg = lane >> 4;

  f4v acc[4][4];
  const f4v zz = {0.f, 0.f, 0.f, 0.f};
  #pragma unroll
  for (int m = 0; m < 4; ++m)
    #pragma unroll
    for (int n = 0; n < 4; ++n) acc[m][n] = zz;

  for (int k0 = 0; k0 < Kd; k0 += BK) {
    GL2LDS16(ga,         la);
    GL2LDS16(ga + rstep, la + 2048);
    GL2LDS16(gb,         lb);
    GL2LDS16(gb + rstep, lb + 2048);
    __syncthreads();
    bf8v af[4], bf_[4];
    #pragma unroll
    for (int m = 0; m < 4; ++m)
      af[m] = *(const bf8v*)&As[wr + m*16 + fr][fg*8];
    #pragma unroll
    for (int n = 0; n < 4; ++n)
      bf_[n] = *(const bf8v*)&Bs[wc + n*16 + fr][fg*8];
    #pragma unroll
    for (int m = 0; m < 4; ++m)
      #pragma unroll
      for (int n = 0; n < 4; ++n)
        acc[m][n] = __builtin_amdgcn_mfma_f32_16x16x32_bf16(af[m], bf_[n], acc[m][n], 0, 0, 0);
    __syncthreads();
    ga += BK; gb += BK;
  }

  float bv[4];
  #pragma unroll
  for (int n = 0; n < 4; ++n) bv[n] = bias[bn + wc + n*16 + fr];
  #pragma unroll
  for (int m = 0; m < 4; ++m) {
    #pragma unroll
    for (int r = 0; r < 4; ++r) {
      const int row = bm + wr + m*16 + fg*4 + r;
      #pragma unroll
      for (int n = 0; n < 4; ++n) {
        const int col = bn + wc + n*16 + fr;
        float x = acc[m][n][r] + bv[n];
        if constexpr (EPI == 1) x = b2f(aux[(size_t)row * N + col]) + scale * x;
        if constexpr (EPI == 2) x = 0.5f * x * (1.f + erff(x * 0.70710678118654752f));
        if constexpr (sizeof(TO) == 2) out[(size_t)row * N + col] = f2b(x);
        else                           out[(size_t)row * N + col] = x;
      }
    }
  }
}

// ---------------- 256^2 depth-3 pipelined MFMA GEMM ------------------------
// counted vmcnt (never drain in steady state), raw s_barrier, T2 swizzle,
// setprio around MFMA cluster. 512 thr = 8 waves (2M x 4N), wave tile 128x64.
template<int EPI, typename TO>
__global__ __launch_bounds__(512, 2) void mgemm256_k(
    const bf16* __restrict__ A, const bf16* __restrict__ Bt,
    const float* __restrict__ bias, const bf16* __restrict__ aux,
    TO* __restrict__ out, int M, int N, int Kd, float scale) {
  constexpr int BM = 256, BN = 256, BK = 32, DEPTH = 3;
  __shared__ bf16 As[DEPTH][BM*BK];   // 3 x 16 KB
  __shared__ bf16 Bs[DEPTH][BN*BK];   // 3 x 16 KB
  const int tid = threadIdx.x;
  const int nMB = M / BM;
  const int nwg = gridDim.x;
  int wg = blockIdx.x;
  wg = (wg & 7) * (nwg >> 3) + (wg >> 3);   // XCD swizzle (nwg % 8 == 0)
  const int bm = (wg % nMB) * BM, bn = (wg / nMB) * BN;

  // staging: thread covers 16B; LDS linear, global source pre-swizzled (T2)
  const int sr = tid >> 2, ss = tid & 3;
  const int sx = ((ss ^ (sr & 3)) * 8);
  const bf16* gA0 = A  + (size_t)(bm + sr)       * Kd + sx;
  const bf16* gA1 = A  + (size_t)(bm + sr + 128) * Kd + sx;
  const bf16* gB0 = Bt + (size_t)(bn + sr)       * Kd + sx;
  const bf16* gB1 = Bt + (size_t)(bn + sr + 128) * Kd + sx;

  const int wid = tid >> 6, lane = tid & 63;
  const int wm = wid >> 2, wn = wid & 3;
  const int fr = lane & 15, fg = lane >> 4;
  const int slot = (fg ^ (fr & 3)) * 8;     // swizzled ds_read slot

  f4v acc[8][4];
  const f4v zz = {0.f, 0.f, 0.f, 0.f};
  #pragma unroll
  for (int m = 0; m < 8; ++m)
    #pragma unroll
    for (int n = 0; n < 4; ++n) acc[m][n] = zz;

  const int nt = Kd / BK;
  // prologue: stage tiles 0..DEPTH-1 (all shapes have nt >= 4)
  #pragma unroll
  for (int p = 0; p < DEPTH; ++p) {
    const int ko = p * BK;
    GL2LDS16(gA0 + ko, &As[p][0] + tid*8);
    GL2LDS16(gA1 + ko, &As[p][0] + tid*8 + 4096);
    GL2LDS16(gB0 + ko, &Bs[p][0] + tid*8);
    GL2LDS16(gB1 + ko, &Bs[p][0] + tid*8 + 4096);
  }

  int bufi = 0;
  for (int t = 0; t < nt; ++t) {
    const int rem = nt - 1 - t;   // staged-ahead tiles still outstanding
    if (rem >= 2)      asm volatile("s_waitcnt vmcnt(8)" ::: "memory");
    else if (rem == 1) asm volatile("s_waitcnt vmcnt(4)" ::: "memory");
    else               asm volatile("s_waitcnt vmcnt(0)" ::: "memory");
    __builtin_amdgcn_s_barrier();            // B1: tile t resident everywhere
    asm volatile("" ::: "memory");
    const bf16* la = &As[bufi][0];
    const bf16* lb = &Bs[bufi][0];
    bf8v af[8], bq[4];
    #pragma unroll
    for (int m = 0; m < 8; ++m)
      af[m] = *(const bf8v*)(la + (wm*128 + m*16 + fr)*BK + slot);
    #pragma unroll
    for (int n = 0; n < 4; ++n)
      bq[n] = *(const bf8v*)(lb + (wn*64 + n*16 + fr)*BK + slot);
    asm volatile("s_waitcnt lgkmcnt(0)" ::: "memory");
    __builtin_amdgcn_s_barrier();            // B2: all waves done reading buf
    asm volatile("" ::: "memory");
    if (t + DEPTH < nt) {                    // prefetch tile t+3 into buf
      const int ko = (t + DEPTH) * BK;
      GL2LDS16(gA0 + ko, &As[bufi][0] + tid*8);
      GL2LDS16(gA1 + ko, &As[bufi][0] + tid*8 + 4096);
      GL2LDS16(gB0 + ko, &Bs[bufi][0] + tid*8);
      GL2LDS16(gB1 + ko, &Bs[bufi][0] + tid*8 + 4096);
    }
    __builtin_amdgcn_s_setprio(1);
    #pragma unroll
    for (int m = 0; m < 8; ++m)
      #pragma unroll
      for (int n = 0; n < 4; ++n)
        acc[m][n] = __builtin_amdgcn_mfma_f32_16x16x32_bf16(af[m], bq[n], acc[m][n], 0, 0, 0);
    __builtin_amdgcn_s_setprio(0);
    bufi = (bufi == DEPTH-1) ? 0 : bufi + 1;
  }

  float bv[4];
  #pragma unroll
  for (int n = 0; n < 4; ++n) bv[n] = bias[bn + wn*64 + n*16 + fr];
  #pragma unroll
  for (int m = 0; m < 8; ++m) {
    #pragma unroll
    for (int r = 0; r < 4; ++r) {
      const int row = bm + wm*128 + m*16 + fg*4 + r;
      #pragma unroll
      for (int n = 0; n < 4; ++n) {
        const int col = bn + wn*64 + n*16 + fr;
        float x = acc[m][n][r] + bv[n];
        if constexpr (EPI == 1) x = b2f(aux[(size_t)row * N + col]) + scale * x;
        if constexpr (EPI == 2) x = 0.5f * x * (1.f + erff(x * 0.70710678118654752f));
        if constexpr (sizeof(TO) == 2) out[(size_t)row * N + col] = f2b(x);
        else                           out[(size_t)row * N + col] = x;
      }
    }
  }
}

__device__ __forceinline__ BF8 pack8(float4 a, float4 b){
  BF8 o;
  o.v[0]=f2b(a.x); o.v[1]=f2b(a.y); o.v[2]=f2b(a.z); o.v[3]=f2b(a.w);
  o.v[4]=f2b(b.x); o.v[5]=f2b(b.y); o.v[6]=f2b(b.z); o.v[7]=f2b(b.w);
  return o;
}

// ---------------- attn2: softmax(S) -> aw, center loss ---------------------
__global__ __launch_bounds__(256) void attn2_k(
    const float* __restrict__ S, const bf16* __restrict__ fn,
    const float* __restrict__ an, const float* __restrict__ na,
    bf16* __restrict__ awp, float* __restrict__ cen_acc) {
  __shared__ bf16 Ab[K_][D_];
  __shared__ float na_s[K_];
  __shared__ float cred[4];
  const int t = threadIdx.x;
  for (int i = t*8; i < K_*D_; i += 2048) {
    float4 a0 = *(const float4*)(an+i), a1 = *(const float4*)(an+i+4);
    *(BF8*)(&Ab[0][0]+i) = pack8(a0, a1);
  }
  if (t < K_) na_s[t] = na[t];
  __syncthreads();
  const int wid = t >> 6, lane = t & 63;
  const int d0 = lane * 16;
  const int sub = lane & 7, head = lane >> 3;
  const int k0 = sub*2, k1 = k0 + 1;
  float na0 = (k0 < K_) ? na_s[k0] : 0.f;
  float na1 = (k1 < K_) ? na_s[k1] : 0.f;
  float c_acc = 0.f;
  const int row0 = blockIdx.x * 32 + wid * 8;

  for (int i = 0; i < 8; ++i) {
    const int row = row0 + i;
    float2 sv = *(const float2*)(S + (size_t)row*128 + head*16 + k0);
    float v0 = (k0 < K_) ? sv.x : -1e30f;
    float v1 = (k1 < K_) ? sv.y : -1e30f;
    float m = fmaxf(v0, v1);
    m = fmaxf(m, __shfl_xor(m,1)); m = fmaxf(m, __shfl_xor(m,2)); m = fmaxf(m, __shfl_xor(m,4));
    float e0 = (k0 < K_) ? __expf(v0 - m) : 0.f;
    float e1 = (k1 < K_) ? __expf(v1 - m) : 0.f;
    float es = e0 + e1;
    es += __shfl_xor(es,1); es += __shfl_xor(es,2); es += __shfl_xor(es,4);
    float inv = 1.f / es;
    float a0 = e0 * inv, a1 = e1 * inv;
    bf16 b0 = f2b(a0), b1 = f2b(a1);
    unsigned int pk = (unsigned int)(*(unsigned short*)&b0)
                    | ((unsigned int)(*(unsigned short*)&b1) << 16);
    *(unsigned int*)(awp + (size_t)row*128 + head*16 + k0) = pk;
    float g0 = a0, g1 = a1;
    g0 += __shfl_xor(g0,8); g0 += __shfl_xor(g0,16); g0 += __shfl_xor(g0,32);
    g1 += __shfl_xor(g1,8); g1 += __shfl_xor(g1,16); g1 += __shfl_xor(g1,32);
    const BF8* fr = (const BF8*)(fn + (size_t)row*D_) + lane*2;
    BF8 f0 = fr[0], f1 = fr[1];
    float fv[16];
    #pragma unroll
    for (int j = 0; j < 8; ++j) { fv[j] = b2f(f0.v[j]); fv[8+j] = b2f(f1.v[j]); }
    float my0 = 0.f, my1 = 0.f;
    #pragma unroll
    for (int k = 0; k < K_; ++k) {
      BF8 aa = *(const BF8*)&Ab[k][d0];
      BF8 ab = *(const BF8*)&Ab[k][d0 + 8];
      float s = 0.f;
      #pragma unroll
      for (int j = 0; j < 8; ++j) {
        s = fmaf(fv[j],   b2f(aa.v[j]), s);
        s = fmaf(fv[8+j], b2f(ab.v[j]), s);
      }
      #pragma unroll
      for (int o = 1; o < 64; o <<= 1) s += __shfl_xor(s, o);
      my0 = (k == k0) ? s : my0;
      my1 = (k == k1) ? s : my1;
    }
    if (sub < 5) {
      float dist0 = sqrtf(fmaxf(1.f + na0 - 2.f*my0, 1e-12f));
      float dist1 = sqrtf(fmaxf(1.f + na1 - 2.f*my1, 1e-12f));
      c_acc = fmaf(g0, dist0, c_acc);
      c_acc = fmaf(g1, dist1, c_acc);
    }
  }
  #pragma unroll
  for (int o = 1; o < 64; o <<= 1) c_acc += __shfl_xor(c_acc, o);
  if (lane == 0) cred[wid] = c_acc;
  __syncthreads();
  if (t == 0) {
    float s = (cred[0]+cred[1]+cred[2]+cred[3]) * (1.f/64.f/(float)B_);
    atomicAdd(cen_acc, s);
  }
}

// ---------------- LayerNorm over rows of bf16 ------------------------------
__global__ __launch_bounds__(256) void ln_k(const bf16* __restrict__ x,
    const float* __restrict__ g, const float* __restrict__ bta,
    bf16* __restrict__ out) {
  int b = blockIdx.x, t = threadIdx.x;
  BF4 ld = ((const BF4*)(x + (size_t)b * D_))[t];
  float v[4];
  #pragma unroll
  for (int j = 0; j < 4; ++j) v[j] = b2f(ld.v[j]);
  float s = v[0]+v[1]+v[2]+v[3];
  #pragma unroll
  for (int o = 32; o > 0; o >>= 1) s += __shfl_down(s, o);
  __shared__ float w1[4], w2[4];
  if ((t & 63) == 0) w1[t >> 6] = s;
  __syncthreads();
  __shared__ float mu_s, rs_s;
  if (t == 0) mu_s = (w1[0]+w1[1]+w1[2]+w1[3]) * (1.f/D_);
  __syncthreads();
  float mu = mu_s;
  float qv = 0.f;
  #pragma unroll
  for (int j = 0; j < 4; ++j) { float d = v[j]-mu; qv += d*d; }
  #pragma unroll
  for (int o = 32; o > 0; o >>= 1) qv += __shfl_down(qv, o);
  if ((t & 63) == 0) w2[t >> 6] = qv;
  __syncthreads();
  if (t == 0) rs_s = rsqrtf((w2[0]+w2[1]+w2[2]+w2[3]) * (1.f/D_) + 1e-5f);
  __syncthreads();
  float rs = rs_s;
  BF4 o;
  #pragma unroll
  for (int j = 0; j < 4; ++j) {
    int col = t*4 + j;
    o.v[j] = f2b((v[j]-mu)*rs*g[col] + bta[col]);
  }
  ((BF4*)(out + (size_t)b * D_))[t] = o;
}

// ---------------- final scalar geo -----------------------------------------
__global__ void geo_k(const float* __restrict__ divl, const float* __restrict__ cen,
                      const float* __restrict__ div_w, const float* __restrict__ cen_w,
                      float* __restrict__ out) {
  float g = fabsf(*div_w) * (*divl) + fabsf(*cen_w) * (*cen);
  out[0] = fminf(fmaxf(g, 0.f), 0.01f);
}

extern "C" void kernel_launch(void* const* d_in, const int* in_sizes, int n_in,
                              void* d_out, int out_size, void* d_ws, size_t ws_size,
                              hipStream_t stream) {
  const float* features = (const float*)d_in[0];
  const float* anchors  = (const float*)d_in[1];
  const float* ar_w1 = (const float*)d_in[2];
  const float* ar_b1 = (const float*)d_in[3];
  const float* ar_w2 = (const float*)d_in[4];
  const float* ar_b2 = (const float*)d_in[5];
  const float* q_w = (const float*)d_in[6];
  const float* q_b = (const float*)d_in[7];
  const float* k_w = (const float*)d_in[8];
  const float* k_b = (const float*)d_in[9];
  const float* v_w = (const float*)d_in[10];
  const float* v_b = (const float*)d_in[11];
  const float* o_w = (const float*)d_in[12];
  const float* o_b = (const float*)d_in[13];
  const float* ln_g = (const float*)d_in[14];
  const float* ln_b = (const float*)d_in[15];
  const float* ff_w1 = (const float*)d_in[16];
  const float* ff_b1 = (const float*)d_in[17];
  const float* ff_w2 = (const float*)d_in[18];
  const float* ff_b2 = (const float*)d_in[19];
  const float* div_w = (const float*)d_in[20];
  const float* cen_w = (const float*)d_in[21];
  float* out = (float*)d_out;

  char* w = (char*)d_ws;
  bf16* ws_fnb = (bf16*)w;  w += (size_t)B_ * D_ * 2;
  bf16* ws_enh = (bf16*)w;  w += (size_t)B_ * D_ * 2;
  bf16* ws_ln  = (bf16*)w;  w += (size_t)B_ * D_ * 2;
  bf16* ws_h   = (bf16*)w;  w += (size_t)B_ * 2048 * 2;
  float* ws_S  = (float*)w; w += (size_t)B_ * 128 * 4;
  bf16* ws_awp = (bf16*)w;  w += (size_t)B_ * 128 * 2;
  bf16* ws_wq  = (bf16*)w;  w += (size_t)D_ * D_ * 2;
  bf16* ws_w1t = (bf16*)w;  w += (size_t)D_ * 2048 * 2;
  bf16* ws_w2t = (bf16*)w;  w += (size_t)2048 * D_ * 2;
  bf16* ws_wt  = (bf16*)w;  w += (size_t)128 * D_ * 2;
  bf16* ws_vt  = (bf16*)w;  w += (size_t)D_ * 128 * 2;
  float* ws_har = (float*)w;  w += (size_t)K_ * (D_/2) * 4;
  float* ws_anu = (float*)w;  w += (size_t)K_ * D_ * 4;
  float* ws_an  = (float*)w;  w += (size_t)K_ * D_ * 4;
  float* ws_k   = (float*)w;  w += (size_t)K_ * D_ * 4;
  float* ws_v   = (float*)w;  w += (size_t)K_ * D_ * 4;
  float* ws_na  = (float*)w;  w += 256;
  float* ws_div = (float*)w;  w += 256;
  float* ws_cen = (float*)w;  w += 256;
  float* ws_sb  = (float*)w;  w += 512;
  if ((size_t)(w - (char*)d_ws) > ws_size) return;

  hipMemsetAsync(ws_cen, 0, 4, stream);

  wt_k<<<dim3(D_/32,   D_/32),   256, 0, stream>>>(q_w,   ws_wq,  D_,   D_);
  wt_k<<<dim3(2048/32, D_/32),   256, 0, stream>>>(ff_w1, ws_w1t, D_,   2048);
  wt_k<<<dim3(D_/32,   2048/32), 256, 0, stream>>>(ff_w2, ws_w2t, 2048, D_);

  l2norm_k<<<B_, 256, 0, stream>>>(features, ws_fnb);

  panelmm_k<32, 1024, 1><<<16, 256, 0, stream>>>(
      anchors, ar_w1, ar_b1, nullptr, ws_har,
      nullptr, nullptr, nullptr, D_/2, 16);
  panelmm_k<64, 512, 2><<<16, 256, 0, stream>>>(
      ws_har, ar_w2, ar_b2, anchors, ws_anu,
      nullptr, nullptr, nullptr, D_, 16);
  ar3_k<<<1, 256, 0, stream>>>(ws_anu, ws_an, ws_na, ws_div);
  panelmm_k<64, 1024, 0><<<32, 256, 0, stream>>>(
      ws_an, k_w, k_b, nullptr, ws_k,
      v_w, v_b, ws_v, D_, 16);

  smallmm_k<0, bf16><<<128, 256, 0, stream>>>(ws_k, ws_wq, ws_wt, 0.08838834764831845f);
  sbias_k<<<1, 128, 0, stream>>>(q_b, ws_k, ws_sb);
  smallmm_k<1, float><<<128, 256, 0, stream>>>(ws_v, o_w, ws_vt, 1.f);

  // S = fn @ W-tilde + sb   [B,128] f32  (N=128 -> 128^2 kernel)
  mgemm_k<0, float><<<dim3((B_/128)*(128/128)), 256, 0, stream>>>(
      ws_fnb, ws_wt, ws_sb, nullptr, ws_S, B_, 128, D_, 0.f);

  attn2_k<<<B_/32, 256, 0, stream>>>(ws_S, ws_fnb, ws_an, ws_na, ws_awp, ws_cen);

  // enh = fn + 0.1*(awp @ V-tilde + o_b)
  mgemm256_k<1, bf16><<<dim3((B_/256)*(D_/256)), 512, 0, stream>>>(
      ws_awp, ws_vt, o_b, ws_fnb, ws_enh, B_, D_, 128, 0.1f);

  ln_k<<<B_, 256, 0, stream>>>(ws_enh, ln_g, ln_b, ws_ln);

  // h = gelu(ln @ ff_w1 + ff_b1)
  mgemm256_k<2, bf16><<<dim3((B_/256)*(2048/256)), 512, 0, stream>>>(
      ws_ln, ws_w1t, ff_b1, nullptr, ws_h, B_, 2048, D_, 0.f);

  // final = fn + 0.2*(h @ ff_w2 + ff_b2) -> d_out (f32)
  mgemm256_k<1, float><<<dim3((B_/256)*(D_/256)), 512, 0, stream>>>(
      ws_h, ws_w2t, ff_b2, ws_fnb, out, B_, D_, 2048, 0.2f);

  geo_k<<<1, 1, 0, stream>>>(ws_div, ws_cen, div_w, cen_w, out + (size_t)B_ * D_);
}